// Round 11
// baseline (174.098 us; speedup 1.0000x reference)
//
#include <hip/hip_runtime.h>
#include <cstdint>

#define NROWS 50000
#define NCLS  91
#define KPRE  1000
#define NDET  100
#define CAP   4096
#define BIN_OFF 62770u      // bin = (bits>>14) - 62770; scores (0.05,1] -> [1,2254]
#define LOGCLAMP 4.135166556742356f
#define P1BLK 3125          // 3125*256 threads = 50000 rows * 16
#define R2BLK 196           // 196 * 256 rows >= 50000
#define NFINE 256           // fine bins per coarse bucket (bucket = bin>>8, 0..8)

// ---- workspace layout (bytes) ----
constexpr size_t OFF_CNT     = 0;        // [1] = compact count
constexpr size_t OFF_ROWMAX  = 64;       // 50000*2
constexpr size_t OFF_COMPACT = 100096;   // CAP*8 = 32768

__device__ __forceinline__ bool decode_box(int row, int c,
    const float* __restrict__ regr, const float* __restrict__ props,
    float W, float H, float4& b) {
  const float4 rr = *reinterpret_cast<const float4*>(regr + (size_t)row * (NCLS * 4) + c * 4);
  const float4 pp = *reinterpret_cast<const float4*>(props + (size_t)row * 4);
  float pw = pp.z - pp.x, ph = pp.w - pp.y;
  float cx = pp.x + 0.5f * pw, cy = pp.y + 0.5f * ph;
  float dx = rr.x / 10.0f, dy = rr.y / 10.0f;
  float dw = fminf(rr.z / 5.0f, LOGCLAMP);
  float dh = fminf(rr.w / 5.0f, LOGCLAMP);
  float pcx = dx * pw + cx, pcy = dy * ph + cy;
  float ppw = expf(dw) * pw, pph = expf(dh) * ph;
  float x1 = fminf(fmaxf(pcx - 0.5f * ppw, 0.f), W);
  float y1 = fminf(fmaxf(pcy - 0.5f * pph, 0.f), H);
  float x2 = fminf(fmaxf(pcx + 0.5f * ppw, 0.f), W);
  float y2 = fminf(fmaxf(pcy + 0.5f * pph, 0.f), H);
  b = make_float4(x1, y1, x2, y2);
  return (x2 - x1 >= 0.01f) && (y2 - y1 >= 0.01f);
}

// K1: 16 threads/row, 6 classes/thread -> per-row max valid bin. Zeroes cnt[1].
__global__ __launch_bounds__(256)
void pass1_kernel(const float* __restrict__ logits,
                  const float* __restrict__ regr,
                  const float* __restrict__ props,
                  const int* __restrict__ p_imh,
                  const int* __restrict__ p_imw,
                  uint16_t* __restrict__ rowmax,
                  uint32_t* __restrict__ cnt) {
  if (blockIdx.x == 0 && threadIdx.x == 0) cnt[1] = 0;
  const int gt  = blockIdx.x * 256 + threadIdx.x;
  const int row = gt >> 4;
  const int sub = gt & 15;
  const float* lr = logits + (size_t)row * NCLS;

  float x[6];
  #pragma unroll
  for (int j = 0; j < 6; ++j) {
    int c = sub + 16 * j;
    x[j] = (c < NCLS) ? lr[c] : -INFINITY;
  }
  float m = x[0];
  #pragma unroll
  for (int j = 1; j < 6; ++j) m = fmaxf(m, x[j]);
  m = fmaxf(m, __shfl_xor(m, 1));
  m = fmaxf(m, __shfl_xor(m, 2));
  m = fmaxf(m, __shfl_xor(m, 4));
  m = fmaxf(m, __shfl_xor(m, 8));
  float e[6]; float s = 0.f;
  #pragma unroll
  for (int j = 0; j < 6; ++j) {
    e[j] = (sub + 16 * j < NCLS) ? expf(x[j] - m) : 0.f;
    s += e[j];
  }
  s += __shfl_xor(s, 1);
  s += __shfl_xor(s, 2);
  s += __shfl_xor(s, 4);
  s += __shfl_xor(s, 8);

  const float W = (float)(*p_imw), H = (float)(*p_imh);
  int maxbin = 0;
  #pragma unroll
  for (int j = 0; j < 6; ++j) {
    int c = sub + 16 * j;
    if (c >= 1 && c < NCLS) {
      float score = e[j] / s;
      if (score > 0.05f) {
        float4 b;
        if (decode_box(row, c, regr, props, W, H, b)) {
          uint32_t bin = (__float_as_uint(score) >> 14) - BIN_OFF;
          if ((int)bin > maxbin) maxbin = (int)bin;
        }
      }
    }
  }
  maxbin = max(maxbin, __shfl_xor(maxbin, 1));
  maxbin = max(maxbin, __shfl_xor(maxbin, 2));
  maxbin = max(maxbin, __shfl_xor(maxbin, 4));
  maxbin = max(maxbin, __shfl_xor(maxbin, 8));
  if (sub == 0) rowmax[row] = (uint16_t)maxbin;
}

// K2: each block derives the cutoff from rowmax WITHOUT histogram atomics:
//   pass A: 9 coarse register counters (bin>>8) -> crossing bucket Bc
//   pass B: 256-bin LDS fine hist, only values inside Bc (few -> cheap)
// Then refines its 256-row slice (op-for-op pass1 arithmetic).
__global__ __launch_bounds__(256)
void refine_kernel(const float* __restrict__ logits,
                   const float* __restrict__ regr,
                   const float* __restrict__ props,
                   const int* __restrict__ p_imh,
                   const int* __restrict__ p_imw,
                   const uint16_t* __restrict__ rowmax,
                   uint32_t* __restrict__ cnt,
                   unsigned long long* __restrict__ compact) {
  __shared__ uint32_t fine[NFINE + 1];
  __shared__ uint32_t cw[4][9];
  __shared__ uint32_t ctot[9];
  __shared__ uint32_t s_cut;
  const int t = threadIdx.x;
  const int lane = t & 63;
  const int wv = t >> 6;

  // ---- pass A: coarse bucket counts in registers ----
  uint32_t c0=0,c1=0,c2=0,c3=0,c4=0,c5=0,c6=0,c7=0,c8=0;
  const uint32_t* r32 = reinterpret_cast<const uint32_t*>(rowmax);
  for (int k = t; k < NROWS / 2; k += 256) {
    uint32_t v = r32[k];
    uint32_t a = v & 0xffffu, b = v >> 16;
    uint32_t ba = a >> 8, bb = b >> 8;
    c0 += ((a != 0u) && (ba == 0u)) + ((b != 0u) && (bb == 0u));
    c1 += (ba == 1u) + (bb == 1u);
    c2 += (ba == 2u) + (bb == 2u);
    c3 += (ba == 3u) + (bb == 3u);
    c4 += (ba == 4u) + (bb == 4u);
    c5 += (ba == 5u) + (bb == 5u);
    c6 += (ba == 6u) + (bb == 6u);
    c7 += (ba == 7u) + (bb == 7u);
    c8 += (ba == 8u) + (bb == 8u);
  }
  #pragma unroll
  for (int off = 32; off; off >>= 1) {
    c0 += __shfl_xor(c0, off); c1 += __shfl_xor(c1, off); c2 += __shfl_xor(c2, off);
    c3 += __shfl_xor(c3, off); c4 += __shfl_xor(c4, off); c5 += __shfl_xor(c5, off);
    c6 += __shfl_xor(c6, off); c7 += __shfl_xor(c7, off); c8 += __shfl_xor(c8, off);
  }
  if (lane == 0) {
    cw[wv][0]=c0; cw[wv][1]=c1; cw[wv][2]=c2; cw[wv][3]=c3; cw[wv][4]=c4;
    cw[wv][5]=c5; cw[wv][6]=c6; cw[wv][7]=c7; cw[wv][8]=c8;
  }
  if (t == 0) s_cut = 0xFFFFFFFFu;
  __syncthreads();
  if (t < 9) ctot[t] = cw[0][t] + cw[1][t] + cw[2][t] + cw[3][t];
  __syncthreads();
  // coarse suffix (every thread, identical)
  uint32_t sfx[10];
  sfx[9] = 0;
  #pragma unroll
  for (int q = 8; q >= 0; --q) sfx[q] = sfx[q + 1] + ctot[q];
  const uint32_t total = sfx[0];
  int Bc = 0;
  uint32_t S_hi = 0, target = 0;
  if (total != 0) {
    target = total < (uint32_t)KPRE ? total : (uint32_t)KPRE;
    #pragma unroll
    for (int q = 8; q >= 0; --q) {
      if (sfx[q] >= target && sfx[q + 1] < target) { Bc = q; S_hi = sfx[q + 1]; }
    }
    // ---- pass B: fine hist inside bucket Bc ----
    if (t < NFINE + 1) fine[t] = 0;
    __syncthreads();
    const uint32_t lo = (uint32_t)Bc << 8;
    for (int k = t; k < NROWS / 2; k += 256) {
      uint32_t v = r32[k];
      uint32_t a = v & 0xffffu, b = v >> 16;
      if (a != 0u && (a >> 8) == (uint32_t)Bc) atomicAdd(&fine[a & 255u], 1u);
      if (b != 0u && (b >> 8) == (uint32_t)Bc) atomicAdd(&fine[b & 255u], 1u);
    }
    __syncthreads();
    // fine suffix scan (in place over 256 entries; fine[256]=0)
    if (t < NFINE) {
      for (int off = 1; off < NFINE; off <<= 1) {
        uint32_t add = (t + off < NFINE) ? fine[t + off] : 0;
        __syncthreads();
        fine[t] += add;
        __syncthreads();
      }
    } else {
      for (int off = 1; off < NFINE; off <<= 1) { __syncthreads(); __syncthreads(); }
    }
    if (t < NFINE) {
      uint32_t hi = S_hi + fine[t];
      uint32_t hin = S_hi + ((t < NFINE - 1) ? fine[t + 1] : 0);
      if (hi >= target && hin < target) s_cut = lo + (uint32_t)t;
    }
    __syncthreads();
  }
  const uint32_t cut = s_cut;

  // ---- refine this block's 256 rows (op-for-op pass1 arithmetic) ----
  const int g16 = lane >> 4;
  const int sub = lane & 15;
  const float W = (float)(*p_imw), H = (float)(*p_imh);
  const int base = blockIdx.x * 256;
  const int myrow0 = base + t;
  bool qual = (myrow0 < NROWS) && ((uint32_t)rowmax[myrow0] >= cut);
  unsigned long long bm = __ballot(qual);
  if (!bm) return;
  const int waveBase = base + (t & ~63);
  while (bm) {
    int bsel[4];
    #pragma unroll
    for (int k = 0; k < 4; ++k) {
      bsel[k] = bm ? (__ffsll((unsigned long long)bm) - 1) : -1;
      if (bm) bm &= bm - 1;
    }
    const int myb = bsel[g16];
    const int row = waveBase + (myb >= 0 ? myb : 0);
    const float* lr = logits + (size_t)row * NCLS;
    float x[6];
    #pragma unroll
    for (int j = 0; j < 6; ++j) {
      int c = sub + 16 * j;
      x[j] = (c < NCLS) ? lr[c] : -INFINITY;
    }
    float m = x[0];
    #pragma unroll
    for (int j = 1; j < 6; ++j) m = fmaxf(m, x[j]);
    m = fmaxf(m, __shfl_xor(m, 1));
    m = fmaxf(m, __shfl_xor(m, 2));
    m = fmaxf(m, __shfl_xor(m, 4));
    m = fmaxf(m, __shfl_xor(m, 8));
    float e[6]; float s = 0.f;
    #pragma unroll
    for (int j = 0; j < 6; ++j) {
      e[j] = (sub + 16 * j < NCLS) ? expf(x[j] - m) : 0.f;
      s += e[j];
    }
    s += __shfl_xor(s, 1);
    s += __shfl_xor(s, 2);
    s += __shfl_xor(s, 4);
    s += __shfl_xor(s, 8);
    if (myb >= 0) {
      #pragma unroll
      for (int j = 0; j < 6; ++j) {
        int c = sub + 16 * j;
        if (c >= 1 && c < NCLS) {
          float score = e[j] / s;
          if (score > 0.05f) {
            float4 bb;
            if (decode_box(row, c, regr, props, W, H, bb)) {
              uint32_t bits = __float_as_uint(score);
              uint32_t bin = (bits >> 14) - BIN_OFF;
              if (bin >= cut) {
                uint32_t pos = atomicAdd(&cnt[1], 1u);
                if (pos < CAP) {
                  uint32_t gidx = (uint32_t)row * 90u + (uint32_t)(c - 1);
                  compact[pos] = ((unsigned long long)bits << 32) |
                                 (unsigned long long)(0xFFFFFFFFu - gidx);
                }
              }
            }
          }
        }
      }
    }
  }
}

__device__ __forceinline__ bool iou_gt(const float4& bi, float areai,
                                       const float4& bj, float areaj) {
  float ltx = fmaxf(bi.x, bj.x), lty = fmaxf(bi.y, bj.y);
  float rbx = fminf(bi.z, bj.z), rby = fminf(bi.w, bj.w);
  float iw = fmaxf(rbx - ltx, 0.f), ih = fmaxf(rby - lty, 0.f);
  float inter = iw * ih;
  float iou = inter / (areai + areaj - inter + 1e-7f);
  return iou > 0.5f;
}

// K3: 1 block, 1024 threads. Bitonic sort -> decode into LDS -> 16-wave mask
// precompute (rows 0..255, reusing sort LDS) -> wave-0 greedy (lazy beyond
// 255, early exit at 100) -> output.
__global__ __launch_bounds__(1024)
void tail_kernel(const float* __restrict__ regr,
                 const float* __restrict__ props,
                 const int* __restrict__ p_imh,
                 const int* __restrict__ p_imw,
                 const uint32_t* __restrict__ cnt,
                 const unsigned long long* __restrict__ compact,
                 float* __restrict__ out) {
  __shared__ unsigned long long arr[CAP];   // 32 KB; reused as mask256
  __shared__ float4 bnms_s[KPRE];           // 16 KB
  __shared__ float  score_s[KPRE];          // 4 KB
  __shared__ uint32_t gidx_s[KPRE];         // 4 KB
  __shared__ int kept[NDET];
  __shared__ int s_kc;
  const int t = threadIdx.x;
  const int lane = t & 63;
  const int wv = t >> 6;
  const float W = (float)(*p_imw), H = (float)(*p_imh);
  const float offmul = (float)(*p_imw + *p_imh + 2);

  const uint32_t Mc = cnt[1];
  const uint32_t M = Mc < (uint32_t)CAP ? Mc : (uint32_t)CAP;
  int P = 1024;
  while (P < (int)M) P <<= 1;
  for (int i = t; i < P; i += 1024) arr[i] = (i < (int)M) ? compact[i] : 0ull;
  __syncthreads();
  for (int k = 2; k <= P; k <<= 1) {
    for (int j = k >> 1; j > 0; j >>= 1) {
      for (int i = t; i < P; i += 1024) {
        int l = i ^ j;
        if (l > i) {
          unsigned long long A = arr[i], B = arr[l];
          bool up = ((i & k) == 0);
          if (up ? (A > B) : (A < B)) { arr[i] = B; arr[l] = A; }
        }
      }
      __syncthreads();
    }
  }
  // decode top-1000 (descending) into LDS
  if (t < KPRE) {
    unsigned long long en = arr[P - 1 - t];
    if (en) {
      float sc = __uint_as_float((uint32_t)(en >> 32));
      uint32_t g = 0xFFFFFFFFu - (uint32_t)en;
      score_s[t] = sc;
      gidx_s[t] = g;
      int row = (int)(g / 90u);
      int c   = (int)(g % 90u) + 1;
      float4 b;
      decode_box(row, c, regr, props, W, H, b);
      float offv = (float)c * offmul;
      bnms_s[t] = make_float4(b.x + offv, b.y + offv, b.z + offv, b.w + offv);
    } else {
      score_s[t] = -1.f;
      gidx_s[t] = 0xFFFFFFFFu;
      bnms_s[t] = make_float4(0, 0, 0, 0);
    }
  }
  if (t == 0) s_kc = 0;
  __syncthreads();   // arr reads done -> safe to reuse as mask256

  // j-side boxes in registers (j = w*64 + lane)
  float4 bj[16];
  float  aj[16];
  #pragma unroll
  for (int w = 0; w < 16; ++w) {
    int j = w * 64 + lane;
    bj[w] = (j < KPRE) ? bnms_s[j] : make_float4(0, 0, 0, 0);
    aj[w] = fmaxf(bj[w].z - bj[w].x, 0.f) * fmaxf(bj[w].w - bj[w].y, 0.f);
  }
  // mask precompute for rows 0..255 across all 16 waves
  unsigned long long* mask256 = arr;        // 256*16*8 = 32768 B
  for (int i = wv; i < 256; i += 16) {
    float4 bi = bnms_s[i];
    float areai = fmaxf(bi.z - bi.x, 0.f) * fmaxf(bi.w - bi.y, 0.f);
    unsigned long long myw = 0ull;
    #pragma unroll
    for (int w = 0; w < 16; ++w) {
      int j = w * 64 + lane;
      bool bit = (j < KPRE) && (j > i) && iou_gt(bi, areai, bj[w], aj[w]);
      unsigned long long mword = __ballot(bit);
      if (lane == w) myw = mword;
    }
    if (lane < 16) mask256[i * 16 + lane] = myw;
  }
  __syncthreads();

  // greedy: wave 0 only, early exit at NDET kept
  if (wv == 0) {
    unsigned long long kw = 0ull;
    #pragma unroll
    for (int w = 0; w < 16; ++w) {
      int j = w * 64 + lane;
      bool b = (j < KPRE) && (score_s[j] > 0.f);
      unsigned long long mword = __ballot(b);
      if (lane == w) kw = mword;
    }
    int kc = 0;
    int i = 0;
    for (; i < 256 && kc < NDET; ++i) {
      unsigned long long kwv = __shfl(kw, i >> 6);
      if ((kwv >> (i & 63)) & 1ull) {
        unsigned long long mrow = (lane < 16) ? mask256[i * 16 + lane] : 0ull;
        if (lane == 0) kept[kc] = i;
        kw &= ~mrow;
        ++kc;
      }
    }
    for (; i < KPRE && kc < NDET; ++i) {    // rare: beyond precomputed range
      unsigned long long kwv = __shfl(kw, i >> 6);
      if ((kwv >> (i & 63)) & 1ull) {
        if (lane == 0) kept[kc] = i;
        float4 bi = bnms_s[i];
        float areai = fmaxf(bi.z - bi.x, 0.f) * fmaxf(bi.w - bi.y, 0.f);
        unsigned long long sup = 0ull;
        #pragma unroll
        for (int w = 0; w < 16; ++w) {
          int j = w * 64 + lane;
          bool bit = (j < KPRE) && (j > i) && iou_gt(bi, areai, bj[w], aj[w]);
          unsigned long long mword = __ballot(bit);
          if (lane == w) sup = mword;
        }
        kw &= ~sup;
        ++kc;
      }
    }
    if (lane == 0) s_kc = kc;
  }
  __syncthreads();

  const int kc = s_kc;
  if (t < NDET) {
    if (t < kc) {
      int i = kept[t];
      uint32_t g = gidx_s[i];
      int row = (int)(g / 90u);
      int c   = (int)(g % 90u) + 1;
      float4 b;
      decode_box(row, c, regr, props, W, H, b);
      out[t * 4 + 0] = b.x; out[t * 4 + 1] = b.y;
      out[t * 4 + 2] = b.z; out[t * 4 + 3] = b.w;
      out[4 * NDET + t] = score_s[i];
      out[5 * NDET + t] = (float)c;
    } else {
      out[t * 4 + 0] = 0.f; out[t * 4 + 1] = 0.f;
      out[t * 4 + 2] = 0.f; out[t * 4 + 3] = 0.f;
      out[4 * NDET + t] = 0.f;
      out[5 * NDET + t] = 0.f;
    }
  }
}

extern "C" void kernel_launch(void* const* d_in, const int* in_sizes, int n_in,
                              void* d_out, int out_size, void* d_ws, size_t ws_size,
                              hipStream_t stream) {
  const float* logits = (const float*)d_in[0];
  const float* regr   = (const float*)d_in[1];
  const float* props  = (const float*)d_in[2];
  const int*   p_imh  = (const int*)d_in[3];
  const int*   p_imw  = (const int*)d_in[4];
  float* out = (float*)d_out;

  uint8_t* ws = (uint8_t*)d_ws;
  uint32_t* cnt  = (uint32_t*)(ws + OFF_CNT);
  uint16_t* rowmax = (uint16_t*)(ws + OFF_ROWMAX);
  unsigned long long* compact = (unsigned long long*)(ws + OFF_COMPACT);

  pass1_kernel<<<P1BLK, 256, 0, stream>>>(
      logits, regr, props, p_imh, p_imw, rowmax, cnt);
  refine_kernel<<<R2BLK, 256, 0, stream>>>(
      logits, regr, props, p_imh, p_imw, rowmax, cnt, compact);
  tail_kernel<<<1, 1024, 0, stream>>>(
      regr, props, p_imh, p_imw, cnt, compact, out);
}

// Round 12
// 119.066 us; speedup vs baseline: 1.4622x; 1.4622x over previous
//
#include <hip/hip_runtime.h>
#include <cstdint>

#define NROWS 50000
#define NCLS  91
#define KPRE  1000
#define NDET  100
#define CAP   4096
#define BIN_OFF 62770u      // bin = (bits>>14) - 62770; scores (0.05,1] -> [1,2254]
#define LOGCLAMP 4.135166556742356f
#define P1BLK 3125          // 3125*256 threads = 50000 rows * 16
#define R2BLK 196           // 196 * 256 rows >= 50000
#define NFINE 256           // fine bins per coarse bucket (bucket = bin>>8, 0..8)
#define GCHUNK 128          // greedy: mask rows per LDS chunk

// ---- workspace layout (bytes) ----
constexpr size_t OFF_CNT     = 0;        // [1] = compact count
constexpr size_t OFF_ROWMAX  = 64;       // 50000*2
constexpr size_t OFF_COMPACT = 100096;   // CAP*8 = 32768
constexpr size_t OFF_SSCORE  = 132864;   // 1024*4
constexpr size_t OFF_SGIDX   = 136960;   // 1024*4
constexpr size_t OFF_SLABEL  = 141056;   // 1024*4
constexpr size_t OFF_BRAW    = 145152;   // 16384
constexpr size_t OFF_BNMS    = 161536;   // 16384
constexpr size_t OFF_MASK    = 177920;   // 1000*16*8 = 128000 -> end ~306 KB

__device__ __forceinline__ bool decode_box(int row, int c,
    const float* __restrict__ regr, const float* __restrict__ props,
    float W, float H, float4& b) {
  const float4 rr = *reinterpret_cast<const float4*>(regr + (size_t)row * (NCLS * 4) + c * 4);
  const float4 pp = *reinterpret_cast<const float4*>(props + (size_t)row * 4);
  float pw = pp.z - pp.x, ph = pp.w - pp.y;
  float cx = pp.x + 0.5f * pw, cy = pp.y + 0.5f * ph;
  float dx = rr.x / 10.0f, dy = rr.y / 10.0f;
  float dw = fminf(rr.z / 5.0f, LOGCLAMP);
  float dh = fminf(rr.w / 5.0f, LOGCLAMP);
  float pcx = dx * pw + cx, pcy = dy * ph + cy;
  float ppw = expf(dw) * pw, pph = expf(dh) * ph;
  float x1 = fminf(fmaxf(pcx - 0.5f * ppw, 0.f), W);
  float y1 = fminf(fmaxf(pcy - 0.5f * pph, 0.f), H);
  float x2 = fminf(fmaxf(pcx + 0.5f * ppw, 0.f), W);
  float y2 = fminf(fmaxf(pcy + 0.5f * pph, 0.f), H);
  b = make_float4(x1, y1, x2, y2);
  return (x2 - x1 >= 0.01f) && (y2 - y1 >= 0.01f);
}

// K1: 16 threads/row, 6 classes/thread -> per-row max valid bin. Zeroes cnt[1].
__global__ __launch_bounds__(256)
void pass1_kernel(const float* __restrict__ logits,
                  const float* __restrict__ regr,
                  const float* __restrict__ props,
                  const int* __restrict__ p_imh,
                  const int* __restrict__ p_imw,
                  uint16_t* __restrict__ rowmax,
                  uint32_t* __restrict__ cnt) {
  if (blockIdx.x == 0 && threadIdx.x == 0) cnt[1] = 0;
  const int gt  = blockIdx.x * 256 + threadIdx.x;
  const int row = gt >> 4;
  const int sub = gt & 15;
  const float* lr = logits + (size_t)row * NCLS;

  float x[6];
  #pragma unroll
  for (int j = 0; j < 6; ++j) {
    int c = sub + 16 * j;
    x[j] = (c < NCLS) ? lr[c] : -INFINITY;
  }
  float m = x[0];
  #pragma unroll
  for (int j = 1; j < 6; ++j) m = fmaxf(m, x[j]);
  m = fmaxf(m, __shfl_xor(m, 1));
  m = fmaxf(m, __shfl_xor(m, 2));
  m = fmaxf(m, __shfl_xor(m, 4));
  m = fmaxf(m, __shfl_xor(m, 8));
  float e[6]; float s = 0.f;
  #pragma unroll
  for (int j = 0; j < 6; ++j) {
    e[j] = (sub + 16 * j < NCLS) ? expf(x[j] - m) : 0.f;
    s += e[j];
  }
  s += __shfl_xor(s, 1);
  s += __shfl_xor(s, 2);
  s += __shfl_xor(s, 4);
  s += __shfl_xor(s, 8);

  const float W = (float)(*p_imw), H = (float)(*p_imh);
  int maxbin = 0;
  #pragma unroll
  for (int j = 0; j < 6; ++j) {
    int c = sub + 16 * j;
    if (c >= 1 && c < NCLS) {
      float score = e[j] / s;
      if (score > 0.05f) {
        float4 b;
        if (decode_box(row, c, regr, props, W, H, b)) {
          uint32_t bin = (__float_as_uint(score) >> 14) - BIN_OFF;
          if ((int)bin > maxbin) maxbin = (int)bin;
        }
      }
    }
  }
  maxbin = max(maxbin, __shfl_xor(maxbin, 1));
  maxbin = max(maxbin, __shfl_xor(maxbin, 2));
  maxbin = max(maxbin, __shfl_xor(maxbin, 4));
  maxbin = max(maxbin, __shfl_xor(maxbin, 8));
  if (sub == 0) rowmax[row] = (uint16_t)maxbin;
}

// K2: each block derives the cutoff from rowmax WITHOUT histogram atomics:
//   pass A: 9 coarse register counters (bin>>8) -> crossing bucket Bc
//   pass B: 256-bin LDS fine hist, only values inside Bc (few -> cheap)
// Then refines its 256-row slice (op-for-op pass1 arithmetic).
__global__ __launch_bounds__(256)
void refine_kernel(const float* __restrict__ logits,
                   const float* __restrict__ regr,
                   const float* __restrict__ props,
                   const int* __restrict__ p_imh,
                   const int* __restrict__ p_imw,
                   const uint16_t* __restrict__ rowmax,
                   uint32_t* __restrict__ cnt,
                   unsigned long long* __restrict__ compact) {
  __shared__ uint32_t fine[NFINE + 1];
  __shared__ uint32_t cw[4][9];
  __shared__ uint32_t ctot[9];
  __shared__ uint32_t s_cut;
  const int t = threadIdx.x;
  const int lane = t & 63;
  const int wv = t >> 6;

  uint32_t c0=0,c1=0,c2=0,c3=0,c4=0,c5=0,c6=0,c7=0,c8=0;
  const uint32_t* r32 = reinterpret_cast<const uint32_t*>(rowmax);
  for (int k = t; k < NROWS / 2; k += 256) {
    uint32_t v = r32[k];
    uint32_t a = v & 0xffffu, b = v >> 16;
    uint32_t ba = a >> 8, bb = b >> 8;
    c0 += ((a != 0u) && (ba == 0u)) + ((b != 0u) && (bb == 0u));
    c1 += (ba == 1u) + (bb == 1u);
    c2 += (ba == 2u) + (bb == 2u);
    c3 += (ba == 3u) + (bb == 3u);
    c4 += (ba == 4u) + (bb == 4u);
    c5 += (ba == 5u) + (bb == 5u);
    c6 += (ba == 6u) + (bb == 6u);
    c7 += (ba == 7u) + (bb == 7u);
    c8 += (ba == 8u) + (bb == 8u);
  }
  #pragma unroll
  for (int off = 32; off; off >>= 1) {
    c0 += __shfl_xor(c0, off); c1 += __shfl_xor(c1, off); c2 += __shfl_xor(c2, off);
    c3 += __shfl_xor(c3, off); c4 += __shfl_xor(c4, off); c5 += __shfl_xor(c5, off);
    c6 += __shfl_xor(c6, off); c7 += __shfl_xor(c7, off); c8 += __shfl_xor(c8, off);
  }
  if (lane == 0) {
    cw[wv][0]=c0; cw[wv][1]=c1; cw[wv][2]=c2; cw[wv][3]=c3; cw[wv][4]=c4;
    cw[wv][5]=c5; cw[wv][6]=c6; cw[wv][7]=c7; cw[wv][8]=c8;
  }
  if (t == 0) s_cut = 0xFFFFFFFFu;
  __syncthreads();
  if (t < 9) ctot[t] = cw[0][t] + cw[1][t] + cw[2][t] + cw[3][t];
  __syncthreads();
  uint32_t sfx[10];
  sfx[9] = 0;
  #pragma unroll
  for (int q = 8; q >= 0; --q) sfx[q] = sfx[q + 1] + ctot[q];
  const uint32_t total = sfx[0];
  int Bc = 0;
  uint32_t S_hi = 0, target = 0;
  if (total != 0) {
    target = total < (uint32_t)KPRE ? total : (uint32_t)KPRE;
    #pragma unroll
    for (int q = 8; q >= 0; --q) {
      if (sfx[q] >= target && sfx[q + 1] < target) { Bc = q; S_hi = sfx[q + 1]; }
    }
    if (t < NFINE + 1) fine[t] = 0;
    __syncthreads();
    const uint32_t lo = (uint32_t)Bc << 8;
    for (int k = t; k < NROWS / 2; k += 256) {
      uint32_t v = r32[k];
      uint32_t a = v & 0xffffu, b = v >> 16;
      if (a != 0u && (a >> 8) == (uint32_t)Bc) atomicAdd(&fine[a & 255u], 1u);
      if (b != 0u && (b >> 8) == (uint32_t)Bc) atomicAdd(&fine[b & 255u], 1u);
    }
    __syncthreads();
    if (t < NFINE) {
      for (int off = 1; off < NFINE; off <<= 1) {
        uint32_t add = (t + off < NFINE) ? fine[t + off] : 0;
        __syncthreads();
        fine[t] += add;
        __syncthreads();
      }
    } else {
      for (int off = 1; off < NFINE; off <<= 1) { __syncthreads(); __syncthreads(); }
    }
    if (t < NFINE) {
      uint32_t hi = S_hi + fine[t];
      uint32_t hin = S_hi + ((t < NFINE - 1) ? fine[t + 1] : 0);
      if (hi >= target && hin < target) s_cut = lo + (uint32_t)t;
    }
    __syncthreads();
  }
  const uint32_t cut = s_cut;

  const int g16 = lane >> 4;
  const int sub = lane & 15;
  const float W = (float)(*p_imw), H = (float)(*p_imh);
  const int base = blockIdx.x * 256;
  const int myrow0 = base + t;
  bool qual = (myrow0 < NROWS) && ((uint32_t)rowmax[myrow0] >= cut);
  unsigned long long bm = __ballot(qual);
  if (!bm) return;
  const int waveBase = base + (t & ~63);
  while (bm) {
    int bsel[4];
    #pragma unroll
    for (int k = 0; k < 4; ++k) {
      bsel[k] = bm ? (__ffsll((unsigned long long)bm) - 1) : -1;
      if (bm) bm &= bm - 1;
    }
    const int myb = bsel[g16];
    const int row = waveBase + (myb >= 0 ? myb : 0);
    const float* lr = logits + (size_t)row * NCLS;
    float x[6];
    #pragma unroll
    for (int j = 0; j < 6; ++j) {
      int c = sub + 16 * j;
      x[j] = (c < NCLS) ? lr[c] : -INFINITY;
    }
    float m = x[0];
    #pragma unroll
    for (int j = 1; j < 6; ++j) m = fmaxf(m, x[j]);
    m = fmaxf(m, __shfl_xor(m, 1));
    m = fmaxf(m, __shfl_xor(m, 2));
    m = fmaxf(m, __shfl_xor(m, 4));
    m = fmaxf(m, __shfl_xor(m, 8));
    float e[6]; float s = 0.f;
    #pragma unroll
    for (int j = 0; j < 6; ++j) {
      e[j] = (sub + 16 * j < NCLS) ? expf(x[j] - m) : 0.f;
      s += e[j];
    }
    s += __shfl_xor(s, 1);
    s += __shfl_xor(s, 2);
    s += __shfl_xor(s, 4);
    s += __shfl_xor(s, 8);
    if (myb >= 0) {
      #pragma unroll
      for (int j = 0; j < 6; ++j) {
        int c = sub + 16 * j;
        if (c >= 1 && c < NCLS) {
          float score = e[j] / s;
          if (score > 0.05f) {
            float4 bb;
            if (decode_box(row, c, regr, props, W, H, bb)) {
              uint32_t bits = __float_as_uint(score);
              uint32_t bin = (bits >> 14) - BIN_OFF;
              if (bin >= cut) {
                uint32_t pos = atomicAdd(&cnt[1], 1u);
                if (pos < CAP) {
                  uint32_t gidx = (uint32_t)row * 90u + (uint32_t)(c - 1);
                  compact[pos] = ((unsigned long long)bits << 32) |
                                 (unsigned long long)(0xFFFFFFFFu - gidx);
                }
              }
            }
          }
        }
      }
    }
  }
}

// K3: 1 block, 1024 threads. Bitonic sort + decode selected to global.
__global__ __launch_bounds__(1024)
void sort_prep_kernel(const unsigned long long* __restrict__ compact,
                      const uint32_t* __restrict__ cnt,
                      const float* __restrict__ regr, const float* __restrict__ props,
                      const int* __restrict__ p_imh, const int* __restrict__ p_imw,
                      float* __restrict__ sel_score, uint32_t* __restrict__ sel_gidx,
                      int* __restrict__ slabel, float4* __restrict__ braw,
                      float4* __restrict__ bnms) {
  __shared__ unsigned long long arr[CAP];
  const int t = threadIdx.x;
  const uint32_t M = cnt[1] < (uint32_t)CAP ? cnt[1] : (uint32_t)CAP;
  int P = 1024;
  while (P < (int)M) P <<= 1;
  for (int i = t; i < P; i += 1024) arr[i] = (i < (int)M) ? compact[i] : 0ull;
  __syncthreads();
  for (int k = 2; k <= P; k <<= 1) {
    for (int j = k >> 1; j > 0; j >>= 1) {
      for (int i = t; i < P; i += 1024) {
        int l = i ^ j;
        if (l > i) {
          unsigned long long A = arr[i], B = arr[l];
          bool up = ((i & k) == 0);
          if (up ? (A > B) : (A < B)) { arr[i] = B; arr[l] = A; }
        }
      }
      __syncthreads();
    }
  }
  if (t < KPRE) {
    unsigned long long en = arr[P - 1 - t];   // descending
    float sc; uint32_t g;
    if (en) { sc = __uint_as_float((uint32_t)(en >> 32)); g = 0xFFFFFFFFu - (uint32_t)en; }
    else    { sc = -1.f; g = 0xFFFFFFFFu; }
    sel_score[t] = sc;
    sel_gidx[t] = g;
    if (sc > 0.f) {
      int row = (int)(g / 90u);
      int c   = (int)(g % 90u) + 1;
      float W = (float)(*p_imw), H = (float)(*p_imh);
      float4 b;
      decode_box(row, c, regr, props, W, H, b);
      braw[t] = b;
      float offv = (float)c * (float)(*p_imw + *p_imh + 2);
      bnms[t] = make_float4(b.x + offv, b.y + offv, b.z + offv, b.w + offv);
      slabel[t] = c;
    } else {
      braw[t] = make_float4(0, 0, 0, 0);
      bnms[t] = make_float4(0, 0, 0, 0);
      slabel[t] = 0;
    }
  }
}

// K4: 1000 blocks x 256: 4 waves x 4 mask-words each.
__global__ __launch_bounds__(256)
void iou_kernel(const float4* __restrict__ bnms, unsigned long long* __restrict__ mask) {
  const int i = blockIdx.x;
  const int lane = threadIdx.x & 63;
  const int wv = threadIdx.x >> 6;
  const float4 bi = bnms[i];
  const float areai = fmaxf(bi.z - bi.x, 0.f) * fmaxf(bi.w - bi.y, 0.f);
  #pragma unroll
  for (int ww = 0; ww < 4; ++ww) {
    int wd = wv * 4 + ww;
    int j = wd * 64 + lane;
    bool bit = false;
    if (j < KPRE && j > i) {
      float4 bj = bnms[j];
      float areaj = fmaxf(bj.z - bj.x, 0.f) * fmaxf(bj.w - bj.y, 0.f);
      float ltx = fmaxf(bi.x, bj.x), lty = fmaxf(bi.y, bj.y);
      float rbx = fminf(bi.z, bj.z), rby = fminf(bi.w, bj.w);
      float iw = fmaxf(rbx - ltx, 0.f), ih = fmaxf(rby - lty, 0.f);
      float inter = iw * ih;
      float iou = inter / (areai + areaj - inter + 1e-7f);
      bit = iou > 0.5f;
    }
    unsigned long long mword = __ballot(bit);
    if (lane == 0) mask[(size_t)i * 16 + wd] = mword;
  }
}

// K5: greedy NMS: wave 0 scans from LDS; waves 1-3 prefetch next chunk.
__global__ __launch_bounds__(256)
void greedy_kernel(const unsigned long long* __restrict__ mask,
                   const float* __restrict__ sel_score,
                   const int* __restrict__ slabel,
                   const float4* __restrict__ braw,
                   float* __restrict__ out) {
  __shared__ ulonglong2 buf[2][GCHUNK * 8];       // 2 x 16 KB
  __shared__ int kept[NDET];
  __shared__ int s_done;
  const int t = threadIdx.x;
  const int lane = t & 63;
  const int wv = t >> 6;
  const ulonglong2* gm2 = reinterpret_cast<const ulonglong2*>(mask);
  constexpr int NCHUNK = (KPRE + GCHUNK - 1) / GCHUNK;   // 8

  unsigned long long kw = 0ull;
  #pragma unroll
  for (int w = 0; w < 16; ++w) {
    int j = w * 64 + lane;
    bool b = (j < KPRE) && (sel_score[j] > 0.f);
    unsigned long long mword = __ballot(b);
    if (lane == w) kw = mword;
  }
  if (t == 0) s_done = 0;

  {
    int rows = (KPRE < GCHUNK) ? KPRE : GCHUNK;
    int n2 = rows * 8;
    for (int k = t; k < n2; k += 256) buf[0][k] = gm2[k];
  }
  __syncthreads();

  int kc = 0;
  for (int c = 0; c < NCHUNK; ++c) {
    if (wv > 0 && c + 1 < NCHUNK) {
      int rows = KPRE - (c + 1) * GCHUNK;
      if (rows > GCHUNK) rows = GCHUNK;
      int n2 = rows * 8;
      size_t gbase = (size_t)(c + 1) * GCHUNK * 8;
      for (int k = t - 64; k < n2; k += 192) buf[(c + 1) & 1][k] = gm2[gbase + k];
    }
    if (wv == 0) {
      const unsigned long long* bb =
          reinterpret_cast<const unsigned long long*>(buf[c & 1]);
      int rows = KPRE - c * GCHUNK;
      if (rows > GCHUNK) rows = GCHUNK;
      unsigned long long curm = (lane < 16) ? bb[lane] : 0ull;
      for (int r = 0; r < rows; ++r) {
        unsigned long long nxt =
            (lane < 16 && r + 1 < rows) ? bb[(r + 1) * 16 + lane] : 0ull;
        int i = c * GCHUNK + r;
        unsigned long long kwv = __shfl(kw, i >> 6);
        if ((kwv >> (i & 63)) & 1ull) {
          if (lane == 0) kept[kc] = i;
          kw &= ~curm;
          ++kc;
          if (kc >= NDET) { if (lane == 0) s_done = 1; break; }
        }
        curm = nxt;
      }
    }
    __syncthreads();
    if (s_done) break;
  }

  if (wv == 0) {
    for (int q = lane; q < NDET; q += 64) {
      if (q < kc) {
        int i = kept[q];
        float4 b = braw[i];
        out[q * 4 + 0] = b.x; out[q * 4 + 1] = b.y;
        out[q * 4 + 2] = b.z; out[q * 4 + 3] = b.w;
        out[4 * NDET + q] = sel_score[i];
        out[5 * NDET + q] = (float)slabel[i];
      } else {
        out[q * 4 + 0] = 0.f; out[q * 4 + 1] = 0.f;
        out[q * 4 + 2] = 0.f; out[q * 4 + 3] = 0.f;
        out[4 * NDET + q] = 0.f;
        out[5 * NDET + q] = 0.f;
      }
    }
  }
}

extern "C" void kernel_launch(void* const* d_in, const int* in_sizes, int n_in,
                              void* d_out, int out_size, void* d_ws, size_t ws_size,
                              hipStream_t stream) {
  const float* logits = (const float*)d_in[0];
  const float* regr   = (const float*)d_in[1];
  const float* props  = (const float*)d_in[2];
  const int*   p_imh  = (const int*)d_in[3];
  const int*   p_imw  = (const int*)d_in[4];
  float* out = (float*)d_out;

  uint8_t* ws = (uint8_t*)d_ws;
  uint32_t* cnt  = (uint32_t*)(ws + OFF_CNT);
  uint16_t* rowmax = (uint16_t*)(ws + OFF_ROWMAX);
  unsigned long long* compact = (unsigned long long*)(ws + OFF_COMPACT);
  float*    sel_score = (float*)(ws + OFF_SSCORE);
  uint32_t* sel_gidx  = (uint32_t*)(ws + OFF_SGIDX);
  int*      slabel    = (int*)(ws + OFF_SLABEL);
  float4*   braw      = (float4*)(ws + OFF_BRAW);
  float4*   bnms      = (float4*)(ws + OFF_BNMS);
  unsigned long long* mask = (unsigned long long*)(ws + OFF_MASK);

  pass1_kernel<<<P1BLK, 256, 0, stream>>>(
      logits, regr, props, p_imh, p_imw, rowmax, cnt);
  refine_kernel<<<R2BLK, 256, 0, stream>>>(
      logits, regr, props, p_imh, p_imw, rowmax, cnt, compact);
  sort_prep_kernel<<<1, 1024, 0, stream>>>(compact, cnt, regr, props, p_imh, p_imw,
                                           sel_score, sel_gidx, slabel, braw, bnms);
  iou_kernel<<<KPRE, 256, 0, stream>>>(bnms, mask);
  greedy_kernel<<<1, 256, 0, stream>>>(mask, sel_score, slabel, braw, out);
}

// Round 13
// 107.243 us; speedup vs baseline: 1.6234x; 1.1102x over previous
//
#include <hip/hip_runtime.h>
#include <cstdint>

#define NROWS 50000
#define NCLS  91
#define KPRE  1000
#define NDET  100
#define CAP   4096
#define BIN_OFF 62770u      // bin = (bits>>14) - 62770; scores (0.05,1] -> [1,2254]
#define LOGCLAMP 4.135166556742356f
#define P1BLK 3125          // 3125*256 threads = 50000 rows * 16
#define R2BLK 196           // 196 * 256 rows >= 50000
#define NFINE 256           // fine bins per coarse bucket (bucket = bin>>8, 0..8)
#define NU4   6250          // rowmax as uint4: 50000*2B / 16B
#define GCHUNK 128          // greedy: mask rows per LDS chunk

// ---- workspace layout (bytes) ----
constexpr size_t OFF_CNT     = 0;        // [1] = compact count
constexpr size_t OFF_ROWMAX  = 64;       // 50000*2 (16B-aligned)
constexpr size_t OFF_COMPACT = 100096;   // CAP*8 = 32768
constexpr size_t OFF_SSCORE  = 132864;   // 1024*4
constexpr size_t OFF_SGIDX   = 136960;   // 1024*4
constexpr size_t OFF_SLABEL  = 141056;   // 1024*4
constexpr size_t OFF_BRAW    = 145152;   // 16384
constexpr size_t OFF_BNMS    = 161536;   // 16384
constexpr size_t OFF_MASK    = 177920;   // 1000*16*8 = 128000 -> end ~306 KB

__device__ __forceinline__ bool decode_box(int row, int c,
    const float* __restrict__ regr, const float* __restrict__ props,
    float W, float H, float4& b) {
  const float4 rr = *reinterpret_cast<const float4*>(regr + (size_t)row * (NCLS * 4) + c * 4);
  const float4 pp = *reinterpret_cast<const float4*>(props + (size_t)row * 4);
  float pw = pp.z - pp.x, ph = pp.w - pp.y;
  float cx = pp.x + 0.5f * pw, cy = pp.y + 0.5f * ph;
  float dx = rr.x / 10.0f, dy = rr.y / 10.0f;
  float dw = fminf(rr.z / 5.0f, LOGCLAMP);
  float dh = fminf(rr.w / 5.0f, LOGCLAMP);
  float pcx = dx * pw + cx, pcy = dy * ph + cy;
  float ppw = expf(dw) * pw, pph = expf(dh) * ph;
  float x1 = fminf(fmaxf(pcx - 0.5f * ppw, 0.f), W);
  float y1 = fminf(fmaxf(pcy - 0.5f * pph, 0.f), H);
  float x2 = fminf(fmaxf(pcx + 0.5f * ppw, 0.f), W);
  float y2 = fminf(fmaxf(pcy + 0.5f * pph, 0.f), H);
  b = make_float4(x1, y1, x2, y2);
  return (x2 - x1 >= 0.01f) && (y2 - y1 >= 0.01f);
}

// K1: 16 threads/row, 6 classes/thread -> per-row max valid bin. Zeroes cnt[1].
__global__ __launch_bounds__(256)
void pass1_kernel(const float* __restrict__ logits,
                  const float* __restrict__ regr,
                  const float* __restrict__ props,
                  const int* __restrict__ p_imh,
                  const int* __restrict__ p_imw,
                  uint16_t* __restrict__ rowmax,
                  uint32_t* __restrict__ cnt) {
  if (blockIdx.x == 0 && threadIdx.x == 0) cnt[1] = 0;
  const int gt  = blockIdx.x * 256 + threadIdx.x;
  const int row = gt >> 4;
  const int sub = gt & 15;
  const float* lr = logits + (size_t)row * NCLS;

  float x[6];
  #pragma unroll
  for (int j = 0; j < 6; ++j) {
    int c = sub + 16 * j;
    x[j] = (c < NCLS) ? lr[c] : -INFINITY;
  }
  float m = x[0];
  #pragma unroll
  for (int j = 1; j < 6; ++j) m = fmaxf(m, x[j]);
  m = fmaxf(m, __shfl_xor(m, 1));
  m = fmaxf(m, __shfl_xor(m, 2));
  m = fmaxf(m, __shfl_xor(m, 4));
  m = fmaxf(m, __shfl_xor(m, 8));
  float e[6]; float s = 0.f;
  #pragma unroll
  for (int j = 0; j < 6; ++j) {
    e[j] = (sub + 16 * j < NCLS) ? expf(x[j] - m) : 0.f;
    s += e[j];
  }
  s += __shfl_xor(s, 1);
  s += __shfl_xor(s, 2);
  s += __shfl_xor(s, 4);
  s += __shfl_xor(s, 8);

  const float W = (float)(*p_imw), H = (float)(*p_imh);
  int maxbin = 0;
  #pragma unroll
  for (int j = 0; j < 6; ++j) {
    int c = sub + 16 * j;
    if (c >= 1 && c < NCLS) {
      float score = e[j] / s;
      if (score > 0.05f) {
        float4 b;
        if (decode_box(row, c, regr, props, W, H, b)) {
          uint32_t bin = (__float_as_uint(score) >> 14) - BIN_OFF;
          if ((int)bin > maxbin) maxbin = (int)bin;
        }
      }
    }
  }
  maxbin = max(maxbin, __shfl_xor(maxbin, 1));
  maxbin = max(maxbin, __shfl_xor(maxbin, 2));
  maxbin = max(maxbin, __shfl_xor(maxbin, 4));
  maxbin = max(maxbin, __shfl_xor(maxbin, 8));
  if (sub == 0) rowmax[row] = (uint16_t)maxbin;
}

// K2: each block derives the cutoff from rowmax with uint4 loads +
// byte-packed coarse counters (no histogram atomics, 4x fewer load stalls),
// then refines its 256-row slice (op-for-op pass1 arithmetic).
__global__ __launch_bounds__(256)
void refine_kernel(const float* __restrict__ logits,
                   const float* __restrict__ regr,
                   const float* __restrict__ props,
                   const int* __restrict__ p_imh,
                   const int* __restrict__ p_imw,
                   const uint16_t* __restrict__ rowmax,
                   uint32_t* __restrict__ cnt,
                   unsigned long long* __restrict__ compact) {
  __shared__ uint32_t fine[NFINE + 1];
  __shared__ uint32_t cw[4][9];
  __shared__ uint32_t ctot[9];
  __shared__ uint32_t s_cut;
  const int t = threadIdx.x;
  const int lane = t & 63;
  const int wv = t >> 6;

  // ---- pass A: coarse bucket counts, byte-packed in one u64 ----
  const uint4* r128 = reinterpret_cast<const uint4*>(rowmax);
  unsigned long long acc = 0ull;
  uint32_t c8 = 0;
  for (int k = t; k < NU4; k += 256) {
    uint4 v = r128[k];
    #pragma unroll
    for (int w = 0; w < 4; ++w) {
      uint32_t u = (w == 0) ? v.x : (w == 1) ? v.y : (w == 2) ? v.z : v.w;
      uint32_t a = u & 0xffffu, b = u >> 16;
      if (a) { uint32_t ba = a >> 8; if (ba < 8u) acc += 1ull << (8u * ba); else ++c8; }
      if (b) { uint32_t bb = b >> 8; if (bb < 8u) acc += 1ull << (8u * bb); else ++c8; }
    }
  }
  uint32_t cc[9];
  #pragma unroll
  for (int q = 0; q < 8; ++q) cc[q] = (uint32_t)((acc >> (8 * q)) & 0xffull);
  cc[8] = c8;
  #pragma unroll
  for (int off = 32; off; off >>= 1) {
    #pragma unroll
    for (int q = 0; q < 9; ++q) cc[q] += __shfl_xor(cc[q], off);
  }
  if (lane == 0) {
    #pragma unroll
    for (int q = 0; q < 9; ++q) cw[wv][q] = cc[q];
  }
  if (t == 0) s_cut = 0xFFFFFFFFu;
  __syncthreads();
  if (t < 9) ctot[t] = cw[0][t] + cw[1][t] + cw[2][t] + cw[3][t];
  __syncthreads();
  uint32_t sfx[10];
  sfx[9] = 0;
  #pragma unroll
  for (int q = 8; q >= 0; --q) sfx[q] = sfx[q + 1] + ctot[q];
  const uint32_t total = sfx[0];
  if (total != 0) {
    const uint32_t target = total < (uint32_t)KPRE ? total : (uint32_t)KPRE;
    int Bc = 0;
    uint32_t S_hi = 0;
    #pragma unroll
    for (int q = 8; q >= 0; --q) {
      if (sfx[q] >= target && sfx[q + 1] < target) { Bc = q; S_hi = sfx[q + 1]; }
    }
    // ---- pass B: fine hist inside bucket Bc (uint4 loads) ----
    if (t < NFINE + 1) fine[t] = 0;
    __syncthreads();
    const uint32_t lo = (uint32_t)Bc << 8;
    for (int k = t; k < NU4; k += 256) {
      uint4 v = r128[k];
      #pragma unroll
      for (int w = 0; w < 4; ++w) {
        uint32_t u = (w == 0) ? v.x : (w == 1) ? v.y : (w == 2) ? v.z : v.w;
        uint32_t a = u & 0xffffu, b = u >> 16;
        if (a && (a >> 8) == (uint32_t)Bc) atomicAdd(&fine[a & 255u], 1u);
        if (b && (b >> 8) == (uint32_t)Bc) atomicAdd(&fine[b & 255u], 1u);
      }
    }
    __syncthreads();
    // fine suffix scan (256 threads, uniform)
    for (int off = 1; off < NFINE; off <<= 1) {
      uint32_t add = (t + off < NFINE) ? fine[t + off] : 0;
      __syncthreads();
      fine[t] += add;
      __syncthreads();
    }
    uint32_t hi = S_hi + fine[t];
    uint32_t hin = S_hi + ((t < NFINE - 1) ? fine[t + 1] : 0);
    if (hi >= target && hin < target) s_cut = lo + (uint32_t)t;
    __syncthreads();
  }
  const uint32_t cut = s_cut;

  // ---- refine this block's 256 rows (op-for-op pass1 arithmetic) ----
  const int g16 = lane >> 4;
  const int sub = lane & 15;
  const float W = (float)(*p_imw), H = (float)(*p_imh);
  const int base = blockIdx.x * 256;
  const int myrow0 = base + t;
  bool qual = (myrow0 < NROWS) && ((uint32_t)rowmax[myrow0] >= cut);
  unsigned long long bm = __ballot(qual);
  if (!bm) return;
  const int waveBase = base + (t & ~63);
  while (bm) {
    int bsel[4];
    #pragma unroll
    for (int k = 0; k < 4; ++k) {
      bsel[k] = bm ? (__ffsll((unsigned long long)bm) - 1) : -1;
      if (bm) bm &= bm - 1;
    }
    const int myb = bsel[g16];
    const int row = waveBase + (myb >= 0 ? myb : 0);
    const float* lr = logits + (size_t)row * NCLS;
    float x[6];
    #pragma unroll
    for (int j = 0; j < 6; ++j) {
      int c = sub + 16 * j;
      x[j] = (c < NCLS) ? lr[c] : -INFINITY;
    }
    float m = x[0];
    #pragma unroll
    for (int j = 1; j < 6; ++j) m = fmaxf(m, x[j]);
    m = fmaxf(m, __shfl_xor(m, 1));
    m = fmaxf(m, __shfl_xor(m, 2));
    m = fmaxf(m, __shfl_xor(m, 4));
    m = fmaxf(m, __shfl_xor(m, 8));
    float e[6]; float s = 0.f;
    #pragma unroll
    for (int j = 0; j < 6; ++j) {
      e[j] = (sub + 16 * j < NCLS) ? expf(x[j] - m) : 0.f;
      s += e[j];
    }
    s += __shfl_xor(s, 1);
    s += __shfl_xor(s, 2);
    s += __shfl_xor(s, 4);
    s += __shfl_xor(s, 8);
    if (myb >= 0) {
      #pragma unroll
      for (int j = 0; j < 6; ++j) {
        int c = sub + 16 * j;
        if (c >= 1 && c < NCLS) {
          float score = e[j] / s;
          if (score > 0.05f) {
            float4 bb;
            if (decode_box(row, c, regr, props, W, H, bb)) {
              uint32_t bits = __float_as_uint(score);
              uint32_t bin = (bits >> 14) - BIN_OFF;
              if (bin >= cut) {
                uint32_t pos = atomicAdd(&cnt[1], 1u);
                if (pos < CAP) {
                  uint32_t gidx = (uint32_t)row * 90u + (uint32_t)(c - 1);
                  compact[pos] = ((unsigned long long)bits << 32) |
                                 (unsigned long long)(0xFFFFFFFFu - gidx);
                }
              }
            }
          }
        }
      }
    }
  }
}

// K3: 1 block, 1024 threads. Bitonic sort + decode selected to global.
__global__ __launch_bounds__(1024)
void sort_prep_kernel(const unsigned long long* __restrict__ compact,
                      const uint32_t* __restrict__ cnt,
                      const float* __restrict__ regr, const float* __restrict__ props,
                      const int* __restrict__ p_imh, const int* __restrict__ p_imw,
                      float* __restrict__ sel_score, uint32_t* __restrict__ sel_gidx,
                      int* __restrict__ slabel, float4* __restrict__ braw,
                      float4* __restrict__ bnms) {
  __shared__ unsigned long long arr[CAP];
  const int t = threadIdx.x;
  const uint32_t M = cnt[1] < (uint32_t)CAP ? cnt[1] : (uint32_t)CAP;
  int P = 1024;
  while (P < (int)M) P <<= 1;
  for (int i = t; i < P; i += 1024) arr[i] = (i < (int)M) ? compact[i] : 0ull;
  __syncthreads();
  for (int k = 2; k <= P; k <<= 1) {
    for (int j = k >> 1; j > 0; j >>= 1) {
      for (int i = t; i < P; i += 1024) {
        int l = i ^ j;
        if (l > i) {
          unsigned long long A = arr[i], B = arr[l];
          bool up = ((i & k) == 0);
          if (up ? (A > B) : (A < B)) { arr[i] = B; arr[l] = A; }
        }
      }
      __syncthreads();
    }
  }
  if (t < KPRE) {
    unsigned long long en = arr[P - 1 - t];   // descending
    float sc; uint32_t g;
    if (en) { sc = __uint_as_float((uint32_t)(en >> 32)); g = 0xFFFFFFFFu - (uint32_t)en; }
    else    { sc = -1.f; g = 0xFFFFFFFFu; }
    sel_score[t] = sc;
    sel_gidx[t] = g;
    if (sc > 0.f) {
      int row = (int)(g / 90u);
      int c   = (int)(g % 90u) + 1;
      float W = (float)(*p_imw), H = (float)(*p_imh);
      float4 b;
      decode_box(row, c, regr, props, W, H, b);
      braw[t] = b;
      float offv = (float)c * (float)(*p_imw + *p_imh + 2);
      bnms[t] = make_float4(b.x + offv, b.y + offv, b.z + offv, b.w + offv);
      slabel[t] = c;
    } else {
      braw[t] = make_float4(0, 0, 0, 0);
      bnms[t] = make_float4(0, 0, 0, 0);
      slabel[t] = 0;
    }
  }
}

// K4: 1000 blocks x 256: 4 waves x 4 mask-words each.
__global__ __launch_bounds__(256)
void iou_kernel(const float4* __restrict__ bnms, unsigned long long* __restrict__ mask) {
  const int i = blockIdx.x;
  const int lane = threadIdx.x & 63;
  const int wv = threadIdx.x >> 6;
  const float4 bi = bnms[i];
  const float areai = fmaxf(bi.z - bi.x, 0.f) * fmaxf(bi.w - bi.y, 0.f);
  #pragma unroll
  for (int ww = 0; ww < 4; ++ww) {
    int wd = wv * 4 + ww;
    int j = wd * 64 + lane;
    bool bit = false;
    if (j < KPRE && j > i) {
      float4 bj = bnms[j];
      float areaj = fmaxf(bj.z - bj.x, 0.f) * fmaxf(bj.w - bj.y, 0.f);
      float ltx = fmaxf(bi.x, bj.x), lty = fmaxf(bi.y, bj.y);
      float rbx = fminf(bi.z, bj.z), rby = fminf(bi.w, bj.w);
      float iw = fmaxf(rbx - ltx, 0.f), ih = fmaxf(rby - lty, 0.f);
      float inter = iw * ih;
      float iou = inter / (areai + areaj - inter + 1e-7f);
      bit = iou > 0.5f;
    }
    unsigned long long mword = __ballot(bit);
    if (lane == 0) mask[(size_t)i * 16 + wd] = mword;
  }
}

// K5: greedy NMS: wave 0 scans from LDS; waves 1-3 prefetch next chunk.
__global__ __launch_bounds__(256)
void greedy_kernel(const unsigned long long* __restrict__ mask,
                   const float* __restrict__ sel_score,
                   const int* __restrict__ slabel,
                   const float4* __restrict__ braw,
                   float* __restrict__ out) {
  __shared__ ulonglong2 buf[2][GCHUNK * 8];       // 2 x 16 KB
  __shared__ int kept[NDET];
  __shared__ int s_done;
  const int t = threadIdx.x;
  const int lane = t & 63;
  const int wv = t >> 6;
  const ulonglong2* gm2 = reinterpret_cast<const ulonglong2*>(mask);
  constexpr int NCHUNK = (KPRE + GCHUNK - 1) / GCHUNK;   // 8

  unsigned long long kw = 0ull;
  #pragma unroll
  for (int w = 0; w < 16; ++w) {
    int j = w * 64 + lane;
    bool b = (j < KPRE) && (sel_score[j] > 0.f);
    unsigned long long mword = __ballot(b);
    if (lane == w) kw = mword;
  }
  if (t == 0) s_done = 0;

  {
    int rows = (KPRE < GCHUNK) ? KPRE : GCHUNK;
    int n2 = rows * 8;
    for (int k = t; k < n2; k += 256) buf[0][k] = gm2[k];
  }
  __syncthreads();

  int kc = 0;
  for (int c = 0; c < NCHUNK; ++c) {
    if (wv > 0 && c + 1 < NCHUNK) {
      int rows = KPRE - (c + 1) * GCHUNK;
      if (rows > GCHUNK) rows = GCHUNK;
      int n2 = rows * 8;
      size_t gbase = (size_t)(c + 1) * GCHUNK * 8;
      for (int k = t - 64; k < n2; k += 192) buf[(c + 1) & 1][k] = gm2[gbase + k];
    }
    if (wv == 0) {
      const unsigned long long* bb =
          reinterpret_cast<const unsigned long long*>(buf[c & 1]);
      int rows = KPRE - c * GCHUNK;
      if (rows > GCHUNK) rows = GCHUNK;
      unsigned long long curm = (lane < 16) ? bb[lane] : 0ull;
      for (int r = 0; r < rows; ++r) {
        unsigned long long nxt =
            (lane < 16 && r + 1 < rows) ? bb[(r + 1) * 16 + lane] : 0ull;
        int i = c * GCHUNK + r;
        unsigned long long kwv = __shfl(kw, i >> 6);
        if ((kwv >> (i & 63)) & 1ull) {
          if (lane == 0) kept[kc] = i;
          kw &= ~curm;
          ++kc;
          if (kc >= NDET) { if (lane == 0) s_done = 1; break; }
        }
        curm = nxt;
      }
    }
    __syncthreads();
    if (s_done) break;
  }

  if (wv == 0) {
    for (int q = lane; q < NDET; q += 64) {
      if (q < kc) {
        int i = kept[q];
        float4 b = braw[i];
        out[q * 4 + 0] = b.x; out[q * 4 + 1] = b.y;
        out[q * 4 + 2] = b.z; out[q * 4 + 3] = b.w;
        out[4 * NDET + q] = sel_score[i];
        out[5 * NDET + q] = (float)slabel[i];
      } else {
        out[q * 4 + 0] = 0.f; out[q * 4 + 1] = 0.f;
        out[q * 4 + 2] = 0.f; out[q * 4 + 3] = 0.f;
        out[4 * NDET + q] = 0.f;
        out[5 * NDET + q] = 0.f;
      }
    }
  }
}

extern "C" void kernel_launch(void* const* d_in, const int* in_sizes, int n_in,
                              void* d_out, int out_size, void* d_ws, size_t ws_size,
                              hipStream_t stream) {
  const float* logits = (const float*)d_in[0];
  const float* regr   = (const float*)d_in[1];
  const float* props  = (const float*)d_in[2];
  const int*   p_imh  = (const int*)d_in[3];
  const int*   p_imw  = (const int*)d_in[4];
  float* out = (float*)d_out;

  uint8_t* ws = (uint8_t*)d_ws;
  uint32_t* cnt  = (uint32_t*)(ws + OFF_CNT);
  uint16_t* rowmax = (uint16_t*)(ws + OFF_ROWMAX);
  unsigned long long* compact = (unsigned long long*)(ws + OFF_COMPACT);
  float*    sel_score = (float*)(ws + OFF_SSCORE);
  uint32_t* sel_gidx  = (uint32_t*)(ws + OFF_SGIDX);
  int*      slabel    = (int*)(ws + OFF_SLABEL);
  float4*   braw      = (float4*)(ws + OFF_BRAW);
  float4*   bnms      = (float4*)(ws + OFF_BNMS);
  unsigned long long* mask = (unsigned long long*)(ws + OFF_MASK);

  pass1_kernel<<<P1BLK, 256, 0, stream>>>(
      logits, regr, props, p_imh, p_imw, rowmax, cnt);
  refine_kernel<<<R2BLK, 256, 0, stream>>>(
      logits, regr, props, p_imh, p_imw, rowmax, cnt, compact);
  sort_prep_kernel<<<1, 1024, 0, stream>>>(compact, cnt, regr, props, p_imh, p_imw,
                                           sel_score, sel_gidx, slabel, braw, bnms);
  iou_kernel<<<KPRE, 256, 0, stream>>>(bnms, mask);
  greedy_kernel<<<1, 256, 0, stream>>>(mask, sel_score, slabel, braw, out);
}

// Round 14
// 91.486 us; speedup vs baseline: 1.9030x; 1.1722x over previous
//
#include <hip/hip_runtime.h>
#include <cstdint>

#define NROWS 50000
#define NCLS  91
#define KPRE  1000
#define NDET  100
#define CAP   4096
#define BIN_OFF 62770u      // bin = (bits>>14) - 62770; scores (0.05,1] -> [1,2254]
#define LOGCLAMP 4.135166556742356f
#define P1BLK 3125          // 3125*256 threads = 50000 rows * 16
#define R2BLK 49            // 49 * 1024 rows >= 50000
#define NFINE 256           // fine bins inside the crossing coarse bucket
#define NU4   6250          // rowmax as uint4: 50000*2B / 16B
#define CPS   3136          // coarse-partial stride (u16) per bucket row
#define CP4   3528          // 9 * 3136/8 uint4 in cpart
#define GCHUNK 128          // greedy: mask rows per LDS chunk

// ---- workspace layout (bytes) ----
constexpr size_t OFF_CNT     = 0;        // [1] = compact count
constexpr size_t OFF_ROWMAX  = 64;       // 50000*2 (16B-aligned)
constexpr size_t OFF_COMPACT = 100096;   // CAP*8 = 32768
constexpr size_t OFF_SSCORE  = 132864;   // 1024*4
constexpr size_t OFF_SGIDX   = 136960;   // 1024*4
constexpr size_t OFF_SLABEL  = 141056;   // 1024*4
constexpr size_t OFF_BRAW    = 145152;   // 16384
constexpr size_t OFF_BNMS    = 161536;   // 16384
constexpr size_t OFF_MASK    = 177920;   // 1000*16*8 = 128000
constexpr size_t OFF_CPART   = 305920;   // 9*3136*2 = 56448 -> end ~362 KB

__device__ __forceinline__ bool decode_box(int row, int c,
    const float* __restrict__ regr, const float* __restrict__ props,
    float W, float H, float4& b) {
  const float4 rr = *reinterpret_cast<const float4*>(regr + (size_t)row * (NCLS * 4) + c * 4);
  const float4 pp = *reinterpret_cast<const float4*>(props + (size_t)row * 4);
  float pw = pp.z - pp.x, ph = pp.w - pp.y;
  float cx = pp.x + 0.5f * pw, cy = pp.y + 0.5f * ph;
  float dx = rr.x / 10.0f, dy = rr.y / 10.0f;
  float dw = fminf(rr.z / 5.0f, LOGCLAMP);
  float dh = fminf(rr.w / 5.0f, LOGCLAMP);
  float pcx = dx * pw + cx, pcy = dy * ph + cy;
  float ppw = expf(dw) * pw, pph = expf(dh) * ph;
  float x1 = fminf(fmaxf(pcx - 0.5f * ppw, 0.f), W);
  float y1 = fminf(fmaxf(pcy - 0.5f * pph, 0.f), H);
  float x2 = fminf(fmaxf(pcx + 0.5f * ppw, 0.f), W);
  float y2 = fminf(fmaxf(pcy + 0.5f * pph, 0.f), H);
  b = make_float4(x1, y1, x2, y2);
  return (x2 - x1 >= 0.01f) && (y2 - y1 >= 0.01f);
}

// K1: 16 threads/row, 6 classes/thread -> per-row max valid bin + per-block
// coarse bucket counts (9 u16 to cpart). Zeroes cnt[1].
__global__ __launch_bounds__(256)
void pass1_kernel(const float* __restrict__ logits,
                  const float* __restrict__ regr,
                  const float* __restrict__ props,
                  const int* __restrict__ p_imh,
                  const int* __restrict__ p_imw,
                  uint16_t* __restrict__ rowmax,
                  uint16_t* __restrict__ cpart,
                  uint32_t* __restrict__ cnt) {
  __shared__ uint32_t lds9[9];
  const int t = threadIdx.x;
  if (blockIdx.x == 0 && t == 0) cnt[1] = 0;
  if (t < 9) lds9[t] = 0;
  __syncthreads();

  const int gt  = blockIdx.x * 256 + t;
  const int row = gt >> 4;
  const int sub = gt & 15;
  const float* lr = logits + (size_t)row * NCLS;

  float x[6];
  #pragma unroll
  for (int j = 0; j < 6; ++j) {
    int c = sub + 16 * j;
    x[j] = (c < NCLS) ? lr[c] : -INFINITY;
  }
  float m = x[0];
  #pragma unroll
  for (int j = 1; j < 6; ++j) m = fmaxf(m, x[j]);
  m = fmaxf(m, __shfl_xor(m, 1));
  m = fmaxf(m, __shfl_xor(m, 2));
  m = fmaxf(m, __shfl_xor(m, 4));
  m = fmaxf(m, __shfl_xor(m, 8));
  float e[6]; float s = 0.f;
  #pragma unroll
  for (int j = 0; j < 6; ++j) {
    e[j] = (sub + 16 * j < NCLS) ? expf(x[j] - m) : 0.f;
    s += e[j];
  }
  s += __shfl_xor(s, 1);
  s += __shfl_xor(s, 2);
  s += __shfl_xor(s, 4);
  s += __shfl_xor(s, 8);

  const float W = (float)(*p_imw), H = (float)(*p_imh);
  int maxbin = 0;
  #pragma unroll
  for (int j = 0; j < 6; ++j) {
    int c = sub + 16 * j;
    if (c >= 1 && c < NCLS) {
      float score = e[j] / s;
      if (score > 0.05f) {
        float4 b;
        if (decode_box(row, c, regr, props, W, H, b)) {
          uint32_t bin = (__float_as_uint(score) >> 14) - BIN_OFF;
          if ((int)bin > maxbin) maxbin = (int)bin;
        }
      }
    }
  }
  maxbin = max(maxbin, __shfl_xor(maxbin, 1));
  maxbin = max(maxbin, __shfl_xor(maxbin, 2));
  maxbin = max(maxbin, __shfl_xor(maxbin, 4));
  maxbin = max(maxbin, __shfl_xor(maxbin, 8));
  if (sub == 0) {
    rowmax[row] = (uint16_t)maxbin;
    if (maxbin > 0) atomicAdd(&lds9[maxbin >> 8], 1u);   // bucket 0..8
  }
  __syncthreads();
  if (t < 9) cpart[(size_t)t * CPS + blockIdx.x] = (uint16_t)lds9[t];
  // blocks 0..8 zero bucket-row pad columns (3125..3135) so refine sums blindly
  if (blockIdx.x < 9 && t < CPS - P1BLK)
    cpart[(size_t)blockIdx.x * CPS + P1BLK + t] = 0;
}

// K2: 49 blocks x 1024. Coarse from cpart (4 iters), ONE fine pass over
// rowmax (7 iters), exact cut, then refine 1024 rows (op-for-op pass1 math).
__global__ __launch_bounds__(1024)
void refine_kernel(const float* __restrict__ logits,
                   const float* __restrict__ regr,
                   const float* __restrict__ props,
                   const int* __restrict__ p_imh,
                   const int* __restrict__ p_imw,
                   const uint16_t* __restrict__ rowmax,
                   const uint16_t* __restrict__ cpart,
                   uint32_t* __restrict__ cnt,
                   unsigned long long* __restrict__ compact) {
  __shared__ uint32_t fine[NFINE + 1];
  __shared__ uint32_t lds9[9];
  __shared__ uint32_t s_cut;
  const int t = threadIdx.x;
  if (t < 9) lds9[t] = 0;
  if (t < NFINE + 1) fine[t] = 0;
  if (t == 0) s_cut = 0xFFFFFFFFu;
  __syncthreads();

  // ---- coarse: sum per-block partials (3528 uint4, 4 iters) ----
  const uint4* cp4 = reinterpret_cast<const uint4*>(cpart);
  for (int k = t; k < CP4; k += 1024) {
    uint4 v = cp4[k];
    uint32_t ssum = (v.x & 0xffffu) + (v.x >> 16) + (v.y & 0xffffu) + (v.y >> 16) +
                    (v.z & 0xffffu) + (v.z >> 16) + (v.w & 0xffffu) + (v.w >> 16);
    if (ssum) atomicAdd(&lds9[k / 392], ssum);     // 392 uint4 per bucket row
  }
  __syncthreads();
  uint32_t sfx[10];
  sfx[9] = 0;
  #pragma unroll
  for (int q = 8; q >= 0; --q) sfx[q] = sfx[q + 1] + lds9[q];
  const uint32_t total = sfx[0];
  uint32_t cut;
  if (total == 0) {
    cut = 0xFFFFFFFFu;
  } else {
    const uint32_t target = total < (uint32_t)KPRE ? total : (uint32_t)KPRE;
    int Bc = 0;
    uint32_t S_hi = 0;
    #pragma unroll
    for (int q = 8; q >= 0; --q) {
      if (sfx[q] >= target && sfx[q + 1] < target) { Bc = q; S_hi = sfx[q + 1]; }
    }
    // ---- fine: one pass over rowmax, only bucket-Bc values (7 iters) ----
    const uint4* r128 = reinterpret_cast<const uint4*>(rowmax);
    for (int k = t; k < NU4; k += 1024) {
      uint4 v = r128[k];
      #pragma unroll
      for (int w = 0; w < 4; ++w) {
        uint32_t u = (w == 0) ? v.x : (w == 1) ? v.y : (w == 2) ? v.z : v.w;
        uint32_t a = u & 0xffffu, b = u >> 16;
        if (a && (a >> 8) == (uint32_t)Bc) atomicAdd(&fine[a & 255u], 1u);
        if (b && (b >> 8) == (uint32_t)Bc) atomicAdd(&fine[b & 255u], 1u);
      }
    }
    __syncthreads();
    for (int off = 1; off < NFINE; off <<= 1) {
      uint32_t add = (t < NFINE && t + off < NFINE) ? fine[t + off] : 0;
      __syncthreads();
      if (t < NFINE) fine[t] += add;
      __syncthreads();
    }
    if (t < NFINE) {
      uint32_t hi = S_hi + fine[t];
      uint32_t hin = S_hi + ((t < NFINE - 1) ? fine[t + 1] : 0);
      if (hi >= target && hin < target) s_cut = ((uint32_t)Bc << 8) + (uint32_t)t;
    }
    __syncthreads();
    cut = s_cut;
  }

  // ---- refine this block's 1024 rows (op-for-op pass1 arithmetic) ----
  const int lane = t & 63;
  const int g16 = lane >> 4;
  const int sub = lane & 15;
  const float W = (float)(*p_imw), H = (float)(*p_imh);
  const int base = blockIdx.x * 1024;
  const int myrow0 = base + t;
  bool qual = (myrow0 < NROWS) && ((uint32_t)rowmax[myrow0] >= cut);
  unsigned long long bm = __ballot(qual);
  if (!bm) return;
  const int waveBase = base + (t & ~63);
  while (bm) {
    int bsel[4];
    #pragma unroll
    for (int k = 0; k < 4; ++k) {
      bsel[k] = bm ? (__ffsll((unsigned long long)bm) - 1) : -1;
      if (bm) bm &= bm - 1;
    }
    const int myb = bsel[g16];
    const int row = waveBase + (myb >= 0 ? myb : 0);
    const float* lr = logits + (size_t)row * NCLS;
    float x[6];
    #pragma unroll
    for (int j = 0; j < 6; ++j) {
      int c = sub + 16 * j;
      x[j] = (c < NCLS) ? lr[c] : -INFINITY;
    }
    float m = x[0];
    #pragma unroll
    for (int j = 1; j < 6; ++j) m = fmaxf(m, x[j]);
    m = fmaxf(m, __shfl_xor(m, 1));
    m = fmaxf(m, __shfl_xor(m, 2));
    m = fmaxf(m, __shfl_xor(m, 4));
    m = fmaxf(m, __shfl_xor(m, 8));
    float e[6]; float s = 0.f;
    #pragma unroll
    for (int j = 0; j < 6; ++j) {
      e[j] = (sub + 16 * j < NCLS) ? expf(x[j] - m) : 0.f;
      s += e[j];
    }
    s += __shfl_xor(s, 1);
    s += __shfl_xor(s, 2);
    s += __shfl_xor(s, 4);
    s += __shfl_xor(s, 8);
    if (myb >= 0) {
      #pragma unroll
      for (int j = 0; j < 6; ++j) {
        int c = sub + 16 * j;
        if (c >= 1 && c < NCLS) {
          float score = e[j] / s;
          if (score > 0.05f) {
            float4 bb;
            if (decode_box(row, c, regr, props, W, H, bb)) {
              uint32_t bits = __float_as_uint(score);
              uint32_t bin = (bits >> 14) - BIN_OFF;
              if (bin >= cut) {
                uint32_t pos = atomicAdd(&cnt[1], 1u);
                if (pos < CAP) {
                  uint32_t gidx = (uint32_t)row * 90u + (uint32_t)(c - 1);
                  compact[pos] = ((unsigned long long)bits << 32) |
                                 (unsigned long long)(0xFFFFFFFFu - gidx);
                }
              }
            }
          }
        }
      }
    }
  }
}

// K3: 1 block, 1024 threads. Bitonic sort + decode selected to global.
__global__ __launch_bounds__(1024)
void sort_prep_kernel(const unsigned long long* __restrict__ compact,
                      const uint32_t* __restrict__ cnt,
                      const float* __restrict__ regr, const float* __restrict__ props,
                      const int* __restrict__ p_imh, const int* __restrict__ p_imw,
                      float* __restrict__ sel_score, uint32_t* __restrict__ sel_gidx,
                      int* __restrict__ slabel, float4* __restrict__ braw,
                      float4* __restrict__ bnms) {
  __shared__ unsigned long long arr[CAP];
  const int t = threadIdx.x;
  const uint32_t M = cnt[1] < (uint32_t)CAP ? cnt[1] : (uint32_t)CAP;
  int P = 1024;
  while (P < (int)M) P <<= 1;
  for (int i = t; i < P; i += 1024) arr[i] = (i < (int)M) ? compact[i] : 0ull;
  __syncthreads();
  for (int k = 2; k <= P; k <<= 1) {
    for (int j = k >> 1; j > 0; j >>= 1) {
      for (int i = t; i < P; i += 1024) {
        int l = i ^ j;
        if (l > i) {
          unsigned long long A = arr[i], B = arr[l];
          bool up = ((i & k) == 0);
          if (up ? (A > B) : (A < B)) { arr[i] = B; arr[l] = A; }
        }
      }
      __syncthreads();
    }
  }
  if (t < KPRE) {
    unsigned long long en = arr[P - 1 - t];   // descending
    float sc; uint32_t g;
    if (en) { sc = __uint_as_float((uint32_t)(en >> 32)); g = 0xFFFFFFFFu - (uint32_t)en; }
    else    { sc = -1.f; g = 0xFFFFFFFFu; }
    sel_score[t] = sc;
    sel_gidx[t] = g;
    if (sc > 0.f) {
      int row = (int)(g / 90u);
      int c   = (int)(g % 90u) + 1;
      float W = (float)(*p_imw), H = (float)(*p_imh);
      float4 b;
      decode_box(row, c, regr, props, W, H, b);
      braw[t] = b;
      float offv = (float)c * (float)(*p_imw + *p_imh + 2);
      bnms[t] = make_float4(b.x + offv, b.y + offv, b.z + offv, b.w + offv);
      slabel[t] = c;
    } else {
      braw[t] = make_float4(0, 0, 0, 0);
      bnms[t] = make_float4(0, 0, 0, 0);
      slabel[t] = 0;
    }
  }
}

// K4: 1000 blocks x 256: 4 waves x 4 mask-words each.
__global__ __launch_bounds__(256)
void iou_kernel(const float4* __restrict__ bnms, unsigned long long* __restrict__ mask) {
  const int i = blockIdx.x;
  const int lane = threadIdx.x & 63;
  const int wv = threadIdx.x >> 6;
  const float4 bi = bnms[i];
  const float areai = fmaxf(bi.z - bi.x, 0.f) * fmaxf(bi.w - bi.y, 0.f);
  #pragma unroll
  for (int ww = 0; ww < 4; ++ww) {
    int wd = wv * 4 + ww;
    int j = wd * 64 + lane;
    bool bit = false;
    if (j < KPRE && j > i) {
      float4 bj = bnms[j];
      float areaj = fmaxf(bj.z - bj.x, 0.f) * fmaxf(bj.w - bj.y, 0.f);
      float ltx = fmaxf(bi.x, bj.x), lty = fmaxf(bi.y, bj.y);
      float rbx = fminf(bi.z, bj.z), rby = fminf(bi.w, bj.w);
      float iw = fmaxf(rbx - ltx, 0.f), ih = fmaxf(rby - lty, 0.f);
      float inter = iw * ih;
      float iou = inter / (areai + areaj - inter + 1e-7f);
      bit = iou > 0.5f;
    }
    unsigned long long mword = __ballot(bit);
    if (lane == 0) mask[(size_t)i * 16 + wd] = mword;
  }
}

// K5: greedy NMS: wave 0 scans from LDS; waves 1-3 prefetch next chunk.
__global__ __launch_bounds__(256)
void greedy_kernel(const unsigned long long* __restrict__ mask,
                   const float* __restrict__ sel_score,
                   const int* __restrict__ slabel,
                   const float4* __restrict__ braw,
                   float* __restrict__ out) {
  __shared__ ulonglong2 buf[2][GCHUNK * 8];       // 2 x 16 KB
  __shared__ int kept[NDET];
  __shared__ int s_done;
  const int t = threadIdx.x;
  const int lane = t & 63;
  const int wv = t >> 6;
  const ulonglong2* gm2 = reinterpret_cast<const ulonglong2*>(mask);
  constexpr int NCHUNK = (KPRE + GCHUNK - 1) / GCHUNK;   // 8

  unsigned long long kw = 0ull;
  #pragma unroll
  for (int w = 0; w < 16; ++w) {
    int j = w * 64 + lane;
    bool b = (j < KPRE) && (sel_score[j] > 0.f);
    unsigned long long mword = __ballot(b);
    if (lane == w) kw = mword;
  }
  if (t == 0) s_done = 0;

  {
    int rows = (KPRE < GCHUNK) ? KPRE : GCHUNK;
    int n2 = rows * 8;
    for (int k = t; k < n2; k += 256) buf[0][k] = gm2[k];
  }
  __syncthreads();

  int kc = 0;
  for (int c = 0; c < NCHUNK; ++c) {
    if (wv > 0 && c + 1 < NCHUNK) {
      int rows = KPRE - (c + 1) * GCHUNK;
      if (rows > GCHUNK) rows = GCHUNK;
      int n2 = rows * 8;
      size_t gbase = (size_t)(c + 1) * GCHUNK * 8;
      for (int k = t - 64; k < n2; k += 192) buf[(c + 1) & 1][k] = gm2[gbase + k];
    }
    if (wv == 0) {
      const unsigned long long* bb =
          reinterpret_cast<const unsigned long long*>(buf[c & 1]);
      int rows = KPRE - c * GCHUNK;
      if (rows > GCHUNK) rows = GCHUNK;
      unsigned long long curm = (lane < 16) ? bb[lane] : 0ull;
      for (int r = 0; r < rows; ++r) {
        unsigned long long nxt =
            (lane < 16 && r + 1 < rows) ? bb[(r + 1) * 16 + lane] : 0ull;
        int i = c * GCHUNK + r;
        unsigned long long kwv = __shfl(kw, i >> 6);
        if ((kwv >> (i & 63)) & 1ull) {
          if (lane == 0) kept[kc] = i;
          kw &= ~curm;
          ++kc;
          if (kc >= NDET) { if (lane == 0) s_done = 1; break; }
        }
        curm = nxt;
      }
    }
    __syncthreads();
    if (s_done) break;
  }

  if (wv == 0) {
    for (int q = lane; q < NDET; q += 64) {
      if (q < kc) {
        int i = kept[q];
        float4 b = braw[i];
        out[q * 4 + 0] = b.x; out[q * 4 + 1] = b.y;
        out[q * 4 + 2] = b.z; out[q * 4 + 3] = b.w;
        out[4 * NDET + q] = sel_score[i];
        out[5 * NDET + q] = (float)slabel[i];
      } else {
        out[q * 4 + 0] = 0.f; out[q * 4 + 1] = 0.f;
        out[q * 4 + 2] = 0.f; out[q * 4 + 3] = 0.f;
        out[4 * NDET + q] = 0.f;
        out[5 * NDET + q] = 0.f;
      }
    }
  }
}

extern "C" void kernel_launch(void* const* d_in, const int* in_sizes, int n_in,
                              void* d_out, int out_size, void* d_ws, size_t ws_size,
                              hipStream_t stream) {
  const float* logits = (const float*)d_in[0];
  const float* regr   = (const float*)d_in[1];
  const float* props  = (const float*)d_in[2];
  const int*   p_imh  = (const int*)d_in[3];
  const int*   p_imw  = (const int*)d_in[4];
  float* out = (float*)d_out;

  uint8_t* ws = (uint8_t*)d_ws;
  uint32_t* cnt  = (uint32_t*)(ws + OFF_CNT);
  uint16_t* rowmax = (uint16_t*)(ws + OFF_ROWMAX);
  unsigned long long* compact = (unsigned long long*)(ws + OFF_COMPACT);
  float*    sel_score = (float*)(ws + OFF_SSCORE);
  uint32_t* sel_gidx  = (uint32_t*)(ws + OFF_SGIDX);
  int*      slabel    = (int*)(ws + OFF_SLABEL);
  float4*   braw      = (float4*)(ws + OFF_BRAW);
  float4*   bnms      = (float4*)(ws + OFF_BNMS);
  unsigned long long* mask = (unsigned long long*)(ws + OFF_MASK);
  uint16_t* cpart     = (uint16_t*)(ws + OFF_CPART);

  pass1_kernel<<<P1BLK, 256, 0, stream>>>(
      logits, regr, props, p_imh, p_imw, rowmax, cpart, cnt);
  refine_kernel<<<R2BLK, 1024, 0, stream>>>(
      logits, regr, props, p_imh, p_imw, rowmax, cpart, cnt, compact);
  sort_prep_kernel<<<1, 1024, 0, stream>>>(compact, cnt, regr, props, p_imh, p_imw,
                                           sel_score, sel_gidx, slabel, braw, bnms);
  iou_kernel<<<KPRE, 256, 0, stream>>>(bnms, mask);
  greedy_kernel<<<1, 256, 0, stream>>>(mask, sel_score, slabel, braw, out);
}

// Round 15
// 90.006 us; speedup vs baseline: 1.9343x; 1.0164x over previous
//
#include <hip/hip_runtime.h>
#include <cstdint>

#define NROWS 50000
#define NCLS  91
#define KPRE  1000
#define NDET  100
#define CAP   4096
#define BIN_OFF 62770u      // bin = (bits>>14) - 62770; scores (0.05,1] -> [1,2254]
#define LOGCLAMP 4.135166556742356f
#define P1BLK 3125          // 3125*256 threads = 50000 rows * 16
#define R2BLK 49            // 49 * 1024 rows >= 50000
#define NFINE 256           // fine bins inside the crossing coarse bucket
#define NU4   6250          // rowmax as uint4: 50000*2B / 16B
#define CPS   3136          // coarse-partial stride (u16) per bucket row
#define CP4   3528          // 9 * 3136/8 uint4 in cpart
#define GCHUNK 128          // greedy: mask rows per LDS chunk

// ---- workspace layout (bytes) ----
constexpr size_t OFF_CNT     = 0;        // [1] = compact count
constexpr size_t OFF_ROWMAX  = 64;       // 50000*2 (16B-aligned)
constexpr size_t OFF_COMPACT = 100096;   // CAP*8 = 32768
constexpr size_t OFF_SSCORE  = 132864;   // 1024*4
constexpr size_t OFF_SGIDX   = 136960;   // 1024*4
constexpr size_t OFF_SLABEL  = 141056;   // 1024*4
constexpr size_t OFF_BRAW    = 145152;   // 16384
constexpr size_t OFF_BNMS    = 161536;   // 16384
constexpr size_t OFF_MASK    = 177920;   // 1000*16*8 = 128000
constexpr size_t OFF_CPART   = 305920;   // 9*3136*2 = 56448 -> end ~362 KB

__device__ __forceinline__ bool decode_box(int row, int c,
    const float* __restrict__ regr, const float* __restrict__ props,
    float W, float H, float4& b) {
  const float4 rr = *reinterpret_cast<const float4*>(regr + (size_t)row * (NCLS * 4) + c * 4);
  const float4 pp = *reinterpret_cast<const float4*>(props + (size_t)row * 4);
  float pw = pp.z - pp.x, ph = pp.w - pp.y;
  float cx = pp.x + 0.5f * pw, cy = pp.y + 0.5f * ph;
  float dx = rr.x / 10.0f, dy = rr.y / 10.0f;
  float dw = fminf(rr.z / 5.0f, LOGCLAMP);
  float dh = fminf(rr.w / 5.0f, LOGCLAMP);
  float pcx = dx * pw + cx, pcy = dy * ph + cy;
  float ppw = expf(dw) * pw, pph = expf(dh) * ph;
  float x1 = fminf(fmaxf(pcx - 0.5f * ppw, 0.f), W);
  float y1 = fminf(fmaxf(pcy - 0.5f * pph, 0.f), H);
  float x2 = fminf(fmaxf(pcx + 0.5f * ppw, 0.f), W);
  float y2 = fminf(fmaxf(pcy + 0.5f * pph, 0.f), H);
  b = make_float4(x1, y1, x2, y2);
  return (x2 - x1 >= 0.01f) && (y2 - y1 >= 0.01f);
}

// Same math as decode_box, operating on preloaded rr/pp values.
__device__ __forceinline__ bool decode_box_v(const float4& rr, const float4& pp,
                                             float W, float H, float4& b) {
  float pw = pp.z - pp.x, ph = pp.w - pp.y;
  float cx = pp.x + 0.5f * pw, cy = pp.y + 0.5f * ph;
  float dx = rr.x / 10.0f, dy = rr.y / 10.0f;
  float dw = fminf(rr.z / 5.0f, LOGCLAMP);
  float dh = fminf(rr.w / 5.0f, LOGCLAMP);
  float pcx = dx * pw + cx, pcy = dy * ph + cy;
  float ppw = expf(dw) * pw, pph = expf(dh) * ph;
  float x1 = fminf(fmaxf(pcx - 0.5f * ppw, 0.f), W);
  float y1 = fminf(fmaxf(pcy - 0.5f * pph, 0.f), H);
  float x2 = fminf(fmaxf(pcx + 0.5f * ppw, 0.f), W);
  float y2 = fminf(fmaxf(pcy + 0.5f * pph, 0.f), H);
  b = make_float4(x1, y1, x2, y2);
  return (x2 - x1 >= 0.01f) && (y2 - y1 >= 0.01f);
}

// K1: 16 threads/row, 6 classes/thread. props prefetched; qualifying regr
// fragments loaded in ONE batched conditional pass (single latency hit),
// then pure-VALU decode. Emits rowmax + per-block coarse bucket partials.
__global__ __launch_bounds__(256)
void pass1_kernel(const float* __restrict__ logits,
                  const float* __restrict__ regr,
                  const float* __restrict__ props,
                  const int* __restrict__ p_imh,
                  const int* __restrict__ p_imw,
                  uint16_t* __restrict__ rowmax,
                  uint16_t* __restrict__ cpart,
                  uint32_t* __restrict__ cnt) {
  __shared__ uint32_t lds9[9];
  const int t = threadIdx.x;
  if (blockIdx.x == 0 && t == 0) cnt[1] = 0;
  if (t < 9) lds9[t] = 0;
  __syncthreads();

  const int gt  = blockIdx.x * 256 + t;
  const int row = gt >> 4;
  const int sub = gt & 15;
  const float* lr = logits + (size_t)row * NCLS;
  const float4 pp = *reinterpret_cast<const float4*>(props + (size_t)row * 4);
  const float W = (float)(*p_imw), H = (float)(*p_imh);

  float x[6];
  #pragma unroll
  for (int j = 0; j < 6; ++j) {
    int c = sub + 16 * j;
    x[j] = (c < NCLS) ? lr[c] : -INFINITY;
  }
  float m = x[0];
  #pragma unroll
  for (int j = 1; j < 6; ++j) m = fmaxf(m, x[j]);
  m = fmaxf(m, __shfl_xor(m, 1));
  m = fmaxf(m, __shfl_xor(m, 2));
  m = fmaxf(m, __shfl_xor(m, 4));
  m = fmaxf(m, __shfl_xor(m, 8));
  float e[6]; float s = 0.f;
  #pragma unroll
  for (int j = 0; j < 6; ++j) {
    e[j] = (sub + 16 * j < NCLS) ? expf(x[j] - m) : 0.f;
    s += e[j];
  }
  s += __shfl_xor(s, 1);
  s += __shfl_xor(s, 2);
  s += __shfl_xor(s, 4);
  s += __shfl_xor(s, 8);

  // batched conditional regr loads: all issued back-to-back, one stall
  const float4* rr4 = reinterpret_cast<const float4*>(regr) + (size_t)row * NCLS;
  float score[6]; bool ok[6]; float4 rrv[6];
  #pragma unroll
  for (int j = 0; j < 6; ++j) {
    int c = sub + 16 * j;
    score[j] = e[j] / s;
    ok[j] = (c >= 1) && (c < NCLS) && (score[j] > 0.05f);
    rrv[j] = ok[j] ? rr4[c] : make_float4(0.f, 0.f, 0.f, 0.f);
  }
  int maxbin = 0;
  #pragma unroll
  for (int j = 0; j < 6; ++j) {
    if (ok[j]) {
      float4 b;
      if (decode_box_v(rrv[j], pp, W, H, b)) {
        uint32_t bin = (__float_as_uint(score[j]) >> 14) - BIN_OFF;
        if ((int)bin > maxbin) maxbin = (int)bin;
      }
    }
  }
  maxbin = max(maxbin, __shfl_xor(maxbin, 1));
  maxbin = max(maxbin, __shfl_xor(maxbin, 2));
  maxbin = max(maxbin, __shfl_xor(maxbin, 4));
  maxbin = max(maxbin, __shfl_xor(maxbin, 8));
  if (sub == 0) {
    rowmax[row] = (uint16_t)maxbin;
    if (maxbin > 0) atomicAdd(&lds9[maxbin >> 8], 1u);   // bucket 0..8
  }
  __syncthreads();
  if (t < 9) cpart[(size_t)t * CPS + blockIdx.x] = (uint16_t)lds9[t];
  if (blockIdx.x < 9 && t < CPS - P1BLK)
    cpart[(size_t)blockIdx.x * CPS + P1BLK + t] = 0;
}

// K2: 49 blocks x 1024. Coarse from cpart (4 iters), ONE fine pass over
// rowmax (7 iters), exact cut, then refine 1024 rows (op-for-op pass1 math).
__global__ __launch_bounds__(1024)
void refine_kernel(const float* __restrict__ logits,
                   const float* __restrict__ regr,
                   const float* __restrict__ props,
                   const int* __restrict__ p_imh,
                   const int* __restrict__ p_imw,
                   const uint16_t* __restrict__ rowmax,
                   const uint16_t* __restrict__ cpart,
                   uint32_t* __restrict__ cnt,
                   unsigned long long* __restrict__ compact) {
  __shared__ uint32_t fine[NFINE + 1];
  __shared__ uint32_t lds9[9];
  __shared__ uint32_t s_cut;
  const int t = threadIdx.x;
  if (t < 9) lds9[t] = 0;
  if (t < NFINE + 1) fine[t] = 0;
  if (t == 0) s_cut = 0xFFFFFFFFu;
  __syncthreads();

  const uint4* cp4 = reinterpret_cast<const uint4*>(cpart);
  for (int k = t; k < CP4; k += 1024) {
    uint4 v = cp4[k];
    uint32_t ssum = (v.x & 0xffffu) + (v.x >> 16) + (v.y & 0xffffu) + (v.y >> 16) +
                    (v.z & 0xffffu) + (v.z >> 16) + (v.w & 0xffffu) + (v.w >> 16);
    if (ssum) atomicAdd(&lds9[k / 392], ssum);     // 392 uint4 per bucket row
  }
  __syncthreads();
  uint32_t sfx[10];
  sfx[9] = 0;
  #pragma unroll
  for (int q = 8; q >= 0; --q) sfx[q] = sfx[q + 1] + lds9[q];
  const uint32_t total = sfx[0];
  uint32_t cut;
  if (total == 0) {
    cut = 0xFFFFFFFFu;
  } else {
    const uint32_t target = total < (uint32_t)KPRE ? total : (uint32_t)KPRE;
    int Bc = 0;
    uint32_t S_hi = 0;
    #pragma unroll
    for (int q = 8; q >= 0; --q) {
      if (sfx[q] >= target && sfx[q + 1] < target) { Bc = q; S_hi = sfx[q + 1]; }
    }
    const uint4* r128 = reinterpret_cast<const uint4*>(rowmax);
    for (int k = t; k < NU4; k += 1024) {
      uint4 v = r128[k];
      #pragma unroll
      for (int w = 0; w < 4; ++w) {
        uint32_t u = (w == 0) ? v.x : (w == 1) ? v.y : (w == 2) ? v.z : v.w;
        uint32_t a = u & 0xffffu, b = u >> 16;
        if (a && (a >> 8) == (uint32_t)Bc) atomicAdd(&fine[a & 255u], 1u);
        if (b && (b >> 8) == (uint32_t)Bc) atomicAdd(&fine[b & 255u], 1u);
      }
    }
    __syncthreads();
    for (int off = 1; off < NFINE; off <<= 1) {
      uint32_t add = (t < NFINE && t + off < NFINE) ? fine[t + off] : 0;
      __syncthreads();
      if (t < NFINE) fine[t] += add;
      __syncthreads();
    }
    if (t < NFINE) {
      uint32_t hi = S_hi + fine[t];
      uint32_t hin = S_hi + ((t < NFINE - 1) ? fine[t + 1] : 0);
      if (hi >= target && hin < target) s_cut = ((uint32_t)Bc << 8) + (uint32_t)t;
    }
    __syncthreads();
    cut = s_cut;
  }

  const int lane = t & 63;
  const int g16 = lane >> 4;
  const int sub = lane & 15;
  const float W = (float)(*p_imw), H = (float)(*p_imh);
  const int base = blockIdx.x * 1024;
  const int myrow0 = base + t;
  bool qual = (myrow0 < NROWS) && ((uint32_t)rowmax[myrow0] >= cut);
  unsigned long long bm = __ballot(qual);
  if (!bm) return;
  const int waveBase = base + (t & ~63);
  while (bm) {
    int bsel[4];
    #pragma unroll
    for (int k = 0; k < 4; ++k) {
      bsel[k] = bm ? (__ffsll((unsigned long long)bm) - 1) : -1;
      if (bm) bm &= bm - 1;
    }
    const int myb = bsel[g16];
    const int row = waveBase + (myb >= 0 ? myb : 0);
    const float* lr = logits + (size_t)row * NCLS;
    float x[6];
    #pragma unroll
    for (int j = 0; j < 6; ++j) {
      int c = sub + 16 * j;
      x[j] = (c < NCLS) ? lr[c] : -INFINITY;
    }
    float m = x[0];
    #pragma unroll
    for (int j = 1; j < 6; ++j) m = fmaxf(m, x[j]);
    m = fmaxf(m, __shfl_xor(m, 1));
    m = fmaxf(m, __shfl_xor(m, 2));
    m = fmaxf(m, __shfl_xor(m, 4));
    m = fmaxf(m, __shfl_xor(m, 8));
    float e[6]; float s = 0.f;
    #pragma unroll
    for (int j = 0; j < 6; ++j) {
      e[j] = (sub + 16 * j < NCLS) ? expf(x[j] - m) : 0.f;
      s += e[j];
    }
    s += __shfl_xor(s, 1);
    s += __shfl_xor(s, 2);
    s += __shfl_xor(s, 4);
    s += __shfl_xor(s, 8);
    if (myb >= 0) {
      #pragma unroll
      for (int j = 0; j < 6; ++j) {
        int c = sub + 16 * j;
        if (c >= 1 && c < NCLS) {
          float score = e[j] / s;
          if (score > 0.05f) {
            float4 bb;
            if (decode_box(row, c, regr, props, W, H, bb)) {
              uint32_t bits = __float_as_uint(score);
              uint32_t bin = (bits >> 14) - BIN_OFF;
              if (bin >= cut) {
                uint32_t pos = atomicAdd(&cnt[1], 1u);
                if (pos < CAP) {
                  uint32_t gidx = (uint32_t)row * 90u + (uint32_t)(c - 1);
                  compact[pos] = ((unsigned long long)bits << 32) |
                                 (unsigned long long)(0xFFFFFFFFu - gidx);
                }
              }
            }
          }
        }
      }
    }
  }
}

// K3: 1 block, 1024 threads. Bitonic sort + decode selected to global.
__global__ __launch_bounds__(1024)
void sort_prep_kernel(const unsigned long long* __restrict__ compact,
                      const uint32_t* __restrict__ cnt,
                      const float* __restrict__ regr, const float* __restrict__ props,
                      const int* __restrict__ p_imh, const int* __restrict__ p_imw,
                      float* __restrict__ sel_score, uint32_t* __restrict__ sel_gidx,
                      int* __restrict__ slabel, float4* __restrict__ braw,
                      float4* __restrict__ bnms) {
  __shared__ unsigned long long arr[CAP];
  const int t = threadIdx.x;
  const uint32_t M = cnt[1] < (uint32_t)CAP ? cnt[1] : (uint32_t)CAP;
  int P = 1024;
  while (P < (int)M) P <<= 1;
  for (int i = t; i < P; i += 1024) arr[i] = (i < (int)M) ? compact[i] : 0ull;
  __syncthreads();
  for (int k = 2; k <= P; k <<= 1) {
    for (int j = k >> 1; j > 0; j >>= 1) {
      for (int i = t; i < P; i += 1024) {
        int l = i ^ j;
        if (l > i) {
          unsigned long long A = arr[i], B = arr[l];
          bool up = ((i & k) == 0);
          if (up ? (A > B) : (A < B)) { arr[i] = B; arr[l] = A; }
        }
      }
      __syncthreads();
    }
  }
  if (t < KPRE) {
    unsigned long long en = arr[P - 1 - t];   // descending
    float sc; uint32_t g;
    if (en) { sc = __uint_as_float((uint32_t)(en >> 32)); g = 0xFFFFFFFFu - (uint32_t)en; }
    else    { sc = -1.f; g = 0xFFFFFFFFu; }
    sel_score[t] = sc;
    sel_gidx[t] = g;
    if (sc > 0.f) {
      int row = (int)(g / 90u);
      int c   = (int)(g % 90u) + 1;
      float W = (float)(*p_imw), H = (float)(*p_imh);
      float4 b;
      decode_box(row, c, regr, props, W, H, b);
      braw[t] = b;
      float offv = (float)c * (float)(*p_imw + *p_imh + 2);
      bnms[t] = make_float4(b.x + offv, b.y + offv, b.z + offv, b.w + offv);
      slabel[t] = c;
    } else {
      braw[t] = make_float4(0, 0, 0, 0);
      bnms[t] = make_float4(0, 0, 0, 0);
      slabel[t] = 0;
    }
  }
}

// K4: 1000 blocks x 256: 4 waves x 4 mask-words each.
__global__ __launch_bounds__(256)
void iou_kernel(const float4* __restrict__ bnms, unsigned long long* __restrict__ mask) {
  const int i = blockIdx.x;
  const int lane = threadIdx.x & 63;
  const int wv = threadIdx.x >> 6;
  const float4 bi = bnms[i];
  const float areai = fmaxf(bi.z - bi.x, 0.f) * fmaxf(bi.w - bi.y, 0.f);
  #pragma unroll
  for (int ww = 0; ww < 4; ++ww) {
    int wd = wv * 4 + ww;
    int j = wd * 64 + lane;
    bool bit = false;
    if (j < KPRE && j > i) {
      float4 bj = bnms[j];
      float areaj = fmaxf(bj.z - bj.x, 0.f) * fmaxf(bj.w - bj.y, 0.f);
      float ltx = fmaxf(bi.x, bj.x), lty = fmaxf(bi.y, bj.y);
      float rbx = fminf(bi.z, bj.z), rby = fminf(bi.w, bj.w);
      float iw = fmaxf(rbx - ltx, 0.f), ih = fmaxf(rby - lty, 0.f);
      float inter = iw * ih;
      float iou = inter / (areai + areaj - inter + 1e-7f);
      bit = iou > 0.5f;
    }
    unsigned long long mword = __ballot(bit);
    if (lane == 0) mask[(size_t)i * 16 + wd] = mword;
  }
}

// K5: greedy NMS: wave 0 scans from LDS; waves 1-3 prefetch next chunk.
__global__ __launch_bounds__(256)
void greedy_kernel(const unsigned long long* __restrict__ mask,
                   const float* __restrict__ sel_score,
                   const int* __restrict__ slabel,
                   const float4* __restrict__ braw,
                   float* __restrict__ out) {
  __shared__ ulonglong2 buf[2][GCHUNK * 8];       // 2 x 16 KB
  __shared__ int kept[NDET];
  __shared__ int s_done;
  const int t = threadIdx.x;
  const int lane = t & 63;
  const int wv = t >> 6;
  const ulonglong2* gm2 = reinterpret_cast<const ulonglong2*>(mask);
  constexpr int NCHUNK = (KPRE + GCHUNK - 1) / GCHUNK;   // 8

  unsigned long long kw = 0ull;
  #pragma unroll
  for (int w = 0; w < 16; ++w) {
    int j = w * 64 + lane;
    bool b = (j < KPRE) && (sel_score[j] > 0.f);
    unsigned long long mword = __ballot(b);
    if (lane == w) kw = mword;
  }
  if (t == 0) s_done = 0;

  {
    int rows = (KPRE < GCHUNK) ? KPRE : GCHUNK;
    int n2 = rows * 8;
    for (int k = t; k < n2; k += 256) buf[0][k] = gm2[k];
  }
  __syncthreads();

  int kc = 0;
  for (int c = 0; c < NCHUNK; ++c) {
    if (wv > 0 && c + 1 < NCHUNK) {
      int rows = KPRE - (c + 1) * GCHUNK;
      if (rows > GCHUNK) rows = GCHUNK;
      int n2 = rows * 8;
      size_t gbase = (size_t)(c + 1) * GCHUNK * 8;
      for (int k = t - 64; k < n2; k += 192) buf[(c + 1) & 1][k] = gm2[gbase + k];
    }
    if (wv == 0) {
      const unsigned long long* bb =
          reinterpret_cast<const unsigned long long*>(buf[c & 1]);
      int rows = KPRE - c * GCHUNK;
      if (rows > GCHUNK) rows = GCHUNK;
      unsigned long long curm = (lane < 16) ? bb[lane] : 0ull;
      for (int r = 0; r < rows; ++r) {
        unsigned long long nxt =
            (lane < 16 && r + 1 < rows) ? bb[(r + 1) * 16 + lane] : 0ull;
        int i = c * GCHUNK + r;
        unsigned long long kwv = __shfl(kw, i >> 6);
        if ((kwv >> (i & 63)) & 1ull) {
          if (lane == 0) kept[kc] = i;
          kw &= ~curm;
          ++kc;
          if (kc >= NDET) { if (lane == 0) s_done = 1; break; }
        }
        curm = nxt;
      }
    }
    __syncthreads();
    if (s_done) break;
  }

  if (wv == 0) {
    for (int q = lane; q < NDET; q += 64) {
      if (q < kc) {
        int i = kept[q];
        float4 b = braw[i];
        out[q * 4 + 0] = b.x; out[q * 4 + 1] = b.y;
        out[q * 4 + 2] = b.z; out[q * 4 + 3] = b.w;
        out[4 * NDET + q] = sel_score[i];
        out[5 * NDET + q] = (float)slabel[i];
      } else {
        out[q * 4 + 0] = 0.f; out[q * 4 + 1] = 0.f;
        out[q * 4 + 2] = 0.f; out[q * 4 + 3] = 0.f;
        out[4 * NDET + q] = 0.f;
        out[5 * NDET + q] = 0.f;
      }
    }
  }
}

extern "C" void kernel_launch(void* const* d_in, const int* in_sizes, int n_in,
                              void* d_out, int out_size, void* d_ws, size_t ws_size,
                              hipStream_t stream) {
  const float* logits = (const float*)d_in[0];
  const float* regr   = (const float*)d_in[1];
  const float* props  = (const float*)d_in[2];
  const int*   p_imh  = (const int*)d_in[3];
  const int*   p_imw  = (const int*)d_in[4];
  float* out = (float*)d_out;

  uint8_t* ws = (uint8_t*)d_ws;
  uint32_t* cnt  = (uint32_t*)(ws + OFF_CNT);
  uint16_t* rowmax = (uint16_t*)(ws + OFF_ROWMAX);
  unsigned long long* compact = (unsigned long long*)(ws + OFF_COMPACT);
  float*    sel_score = (float*)(ws + OFF_SSCORE);
  uint32_t* sel_gidx  = (uint32_t*)(ws + OFF_SGIDX);
  int*      slabel    = (int*)(ws + OFF_SLABEL);
  float4*   braw      = (float4*)(ws + OFF_BRAW);
  float4*   bnms      = (float4*)(ws + OFF_BNMS);
  unsigned long long* mask = (unsigned long long*)(ws + OFF_MASK);
  uint16_t* cpart     = (uint16_t*)(ws + OFF_CPART);

  pass1_kernel<<<P1BLK, 256, 0, stream>>>(
      logits, regr, props, p_imh, p_imw, rowmax, cpart, cnt);
  refine_kernel<<<R2BLK, 1024, 0, stream>>>(
      logits, regr, props, p_imh, p_imw, rowmax, cpart, cnt, compact);
  sort_prep_kernel<<<1, 1024, 0, stream>>>(compact, cnt, regr, props, p_imh, p_imw,
                                           sel_score, sel_gidx, slabel, braw, bnms);
  iou_kernel<<<KPRE, 256, 0, stream>>>(bnms, mask);
  greedy_kernel<<<1, 256, 0, stream>>>(mask, sel_score, slabel, braw, out);
}